// Round 2
// baseline (670.221 us; speedup 1.0000x reference)
//
#include <hip/hip_runtime.h>

// ---------------------------------------------------------------------------
// GATv2 x2 + classifier. N=50000, E=800000, IN=128, HEADS=4, HID=32, OUT=16.
// R2: (a) gat_attn with 4 independent online-softmax states (ILP for the
//     latency-bound edge loop), log2-domain softmax;
//     (b) fused dual GEMM (xl+xr in one pass, 128-row tile, 8x8x2 per thread);
//     (c) wpos init fused into scan.
// ---------------------------------------------------------------------------

#define LOG2E 1.4426950408889634f

__global__ __launch_bounds__(256) void zero_i32(int* __restrict__ p, int n) {
  int i = blockIdx.x * 256 + threadIdx.x;
  if (i < n) p[i] = 0;
}

__global__ __launch_bounds__(256) void count_kernel(const int* __restrict__ dst,
                                                    int* __restrict__ cnt, int E) {
  int i = blockIdx.x * 256 + threadIdx.x;
  if (i < E) atomicAdd(&cnt[dst[i]], 1);
}

// single-block exclusive scan over n<=1024*CH counts -> row_start[0..n], wpos
__global__ __launch_bounds__(1024) void scan_kernel(const int* __restrict__ cnt,
                                                    int* __restrict__ row_start,
                                                    int* __restrict__ wpos, int n) {
  __shared__ int s[1024];
  int t = threadIdx.x;
  int CH = (n + 1023) >> 10;
  int base = t * CH;
  int lim = min(base + CH, n);
  int sum = 0;
  for (int i = base; i < lim; ++i) sum += cnt[i];
  s[t] = sum;
  __syncthreads();
  for (int off = 1; off < 1024; off <<= 1) {
    int v = (t >= off) ? s[t - off] : 0;
    __syncthreads();
    s[t] += v;
    __syncthreads();
  }
  int run = s[t] - sum;  // exclusive prefix
  for (int i = base; i < lim; ++i) {
    row_start[i] = run;
    wpos[i] = run;
    run += cnt[i];
  }
  if (t == 1023) row_start[n] = s[1023];
}

__global__ __launch_bounds__(256) void scatter_kernel(const int* __restrict__ src,
                                                      const int* __restrict__ dst,
                                                      int* __restrict__ wpos,
                                                      int* __restrict__ csr, int E) {
  int i = blockIdx.x * 256 + threadIdx.x;
  if (i < E) {
    int d = dst[i];
    int p = atomicAdd(&wpos[d], 1);
    csr[p] = src[i];
  }
}

// Cl = A@Wl, Cr = A@Wr  (A: nrows x 128, W: 128 x 128), fp32.
// 128-row tile/block, 256 thr, each thread 8 rows x 8 cols x 2 outputs.
__global__ __launch_bounds__(256, 2) void gemm_dual(const float* __restrict__ A,
                                                    const float* __restrict__ Wl,
                                                    const float* __restrict__ Wr,
                                                    float* __restrict__ Cl,
                                                    float* __restrict__ Cr, int nrows) {
  __shared__ float sA[128 * 33];
  __shared__ __align__(16) float sWl[32 * 128];
  __shared__ __align__(16) float sWr[32 * 128];
  int tid = threadIdx.x;
  int rowBase = blockIdx.x * 128;
  int tx = tid & 15, ty = tid >> 4;
  int c0 = tx * 8;
  int r0 = ty * 8;
  float accl[8][8], accr[8][8];
#pragma unroll
  for (int j = 0; j < 8; ++j)
#pragma unroll
    for (int i = 0; i < 8; ++i) { accl[j][i] = 0.f; accr[j][i] = 0.f; }

  for (int kc = 0; kc < 4; ++kc) {
    // A tile: 128 rows x 32 k = 1024 float4, 4 per thread
#pragma unroll
    for (int i = 0; i < 4; ++i) {
      int idx = tid + i * 256;  // 0..1023
      int row = idx >> 3, f4 = idx & 7;
      float4 v = make_float4(0.f, 0.f, 0.f, 0.f);
      int gr = rowBase + row;
      if (gr < nrows) v = *(const float4*)&A[(size_t)gr * 128 + kc * 32 + f4 * 4];
      int o = row * 33 + f4 * 4;
      sA[o] = v.x; sA[o + 1] = v.y; sA[o + 2] = v.z; sA[o + 3] = v.w;
    }
    // W tiles: 32 k x 128 cols = 1024 float4 each, 4 per thread each
#pragma unroll
    for (int i = 0; i < 4; ++i) {
      int idx = tid + i * 256;
      int k = idx >> 5, f4 = idx & 31;
      *(float4*)&sWl[k * 128 + f4 * 4] =
          *(const float4*)&Wl[(size_t)(kc * 32 + k) * 128 + f4 * 4];
      *(float4*)&sWr[k * 128 + f4 * 4] =
          *(const float4*)&Wr[(size_t)(kc * 32 + k) * 128 + f4 * 4];
    }
    __syncthreads();
#pragma unroll
    for (int kk = 0; kk < 32; ++kk) {
      float a[8];
#pragma unroll
      for (int j = 0; j < 8; ++j) a[j] = sA[(r0 + j) * 33 + kk];
      float4 wl0 = *(const float4*)&sWl[kk * 128 + c0];
      float4 wl1 = *(const float4*)&sWl[kk * 128 + c0 + 4];
      float4 wr0 = *(const float4*)&sWr[kk * 128 + c0];
      float4 wr1 = *(const float4*)&sWr[kk * 128 + c0 + 4];
      float wl[8] = {wl0.x, wl0.y, wl0.z, wl0.w, wl1.x, wl1.y, wl1.z, wl1.w};
      float wr[8] = {wr0.x, wr0.y, wr0.z, wr0.w, wr1.x, wr1.y, wr1.z, wr1.w};
#pragma unroll
      for (int j = 0; j < 8; ++j) {
#pragma unroll
        for (int i = 0; i < 8; ++i) {
          accl[j][i] = fmaf(a[j], wl[i], accl[j][i]);
          accr[j][i] = fmaf(a[j], wr[i], accr[j][i]);
        }
      }
    }
    __syncthreads();
  }
#pragma unroll
  for (int j = 0; j < 8; ++j) {
    int gr = rowBase + r0 + j;
    if (gr < nrows) {
      *(float4*)&Cl[(size_t)gr * 128 + c0] =
          make_float4(accl[j][0], accl[j][1], accl[j][2], accl[j][3]);
      *(float4*)&Cl[(size_t)gr * 128 + c0 + 4] =
          make_float4(accl[j][4], accl[j][5], accl[j][6], accl[j][7]);
      *(float4*)&Cr[(size_t)gr * 128 + c0] =
          make_float4(accr[j][0], accr[j][1], accr[j][2], accr[j][3]);
      *(float4*)&Cr[(size_t)gr * 128 + c0 + 4] =
          make_float4(accr[j][4], accr[j][5], accr[j][6], accr[j][7]);
    }
  }
}

// One wave per node; lane handles channels (2*lane, 2*lane+1), head = lane/16.
// 4 independent online-softmax states (edge i -> state i%4), merged at end.
__global__ __launch_bounds__(256) void gat_attn(const float* __restrict__ xl,
                                                const float* __restrict__ xr,
                                                const int* __restrict__ row_start,
                                                const int* __restrict__ csr,
                                                const float* __restrict__ att,
                                                const float* __restrict__ bias,
                                                float* __restrict__ out, int n_nodes) {
  int node = blockIdx.x * 4 + (threadIdx.x >> 6);
  if (node >= n_nodes) return;
  int lane = threadIdx.x & 63;
  int c = lane * 2;
  float2 xrd = *(const float2*)&xr[(size_t)node * 128 + c];
  float ax = att[c], ay = att[c + 1];

  float m[4], l[4], sx[4], sy[4];
  // self loop -> state 0
  {
    float2 xs = *(const float2*)&xl[(size_t)node * 128 + c];
    float t0 = xs.x + xrd.x; t0 = (t0 > 0.f) ? t0 : 0.2f * t0;
    float t1 = xs.y + xrd.y; t1 = (t1 > 0.f) ? t1 : 0.2f * t1;
    float t = t0 * ax + t1 * ay;
    t += __shfl_xor(t, 1); t += __shfl_xor(t, 2);
    t += __shfl_xor(t, 4); t += __shfl_xor(t, 8);
    m[0] = t * LOG2E; l[0] = 1.f; sx[0] = xs.x; sy[0] = xs.y;
  }
#pragma unroll
  for (int k = 1; k < 4; ++k) { m[k] = -1e30f; l[k] = 0.f; sx[k] = 0.f; sy[k] = 0.f; }

  int beg = row_start[node], end = row_start[node + 1];
  for (int i = beg; i < end; i += 4) {
    int srcs[4];
    float2 xs[4];
    float e[4];
#pragma unroll
    for (int j = 0; j < 4; ++j) srcs[j] = (i + j < end) ? csr[i + j] : node;
#pragma unroll
    for (int j = 0; j < 4; ++j)
      xs[j] = *(const float2*)&xl[(size_t)srcs[j] * 128 + c];
#pragma unroll
    for (int j = 0; j < 4; ++j) {
      float t0 = xs[j].x + xrd.x; t0 = (t0 > 0.f) ? t0 : 0.2f * t0;
      float t1 = xs[j].y + xrd.y; t1 = (t1 > 0.f) ? t1 : 0.2f * t1;
      float t = t0 * ax + t1 * ay;
      t += __shfl_xor(t, 1); t += __shfl_xor(t, 2);
      t += __shfl_xor(t, 4); t += __shfl_xor(t, 8);
      e[j] = (i + j < end) ? t * LOG2E : -2e30f;  // masked: p -> exp2(-1e30) = 0
    }
#pragma unroll
    for (int j = 0; j < 4; ++j) {
      float nm = fmaxf(m[j], e[j]);
      float s = exp2f(m[j] - nm);
      float p = exp2f(e[j] - nm);
      l[j] = l[j] * s + p;
      sx[j] = sx[j] * s + p * xs[j].x;
      sy[j] = sy[j] * s + p * xs[j].y;
      m[j] = nm;
    }
  }
  // merge states: 1->0, 3->2, 2->0
#pragma unroll
  for (int step = 0; step < 3; ++step) {
    int a = (step == 0) ? 0 : (step == 1) ? 2 : 0;
    int b = (step == 0) ? 1 : (step == 1) ? 3 : 2;
    float nm = fmaxf(m[a], m[b]);
    float s0 = exp2f(m[a] - nm), s1 = exp2f(m[b] - nm);
    l[a] = l[a] * s0 + l[b] * s1;
    sx[a] = sx[a] * s0 + sx[b] * s1;
    sy[a] = sy[a] * s0 + sy[b] * s1;
    m[a] = nm;
  }
  float inv = 1.f / (l[0] + 1e-16f);
  float ox = sx[0] * inv + bias[c];
  float oy = sy[0] * inv + bias[c + 1];
  ox = (ox > 0.f) ? ox : 0.01f * ox;
  oy = (oy > 0.f) ? oy : 0.01f * oy;
  *(float2*)&out[(size_t)node * 128 + c] = make_float2(ox, oy);
}

__global__ __launch_bounds__(256) void classifier_kernel(const float* __restrict__ h,
                                                         const float* __restrict__ Wc,
                                                         const float* __restrict__ bc,
                                                         float* __restrict__ logits,
                                                         int n) {
  int idx = blockIdx.x * 256 + threadIdx.x;
  if (idx >= n * 16) return;
  int node = idx >> 4, o = idx & 15;
  float acc = bc[o];
  const float* hrow = &h[(size_t)node * 128];
#pragma unroll
  for (int cc = 0; cc < 128; ++cc) acc = fmaf(hrow[cc], Wc[cc * 16 + o], acc);
  logits[idx] = acc;
}

extern "C" void kernel_launch(void* const* d_in, const int* in_sizes, int n_in,
                              void* d_out, int out_size, void* d_ws, size_t ws_size,
                              hipStream_t stream) {
  const float* x    = (const float*)d_in[0];
  const int*   ei   = (const int*)d_in[1];
  const float* Wl1  = (const float*)d_in[3];
  const float* Wr1  = (const float*)d_in[4];
  const float* att1 = (const float*)d_in[5];
  const float* b1   = (const float*)d_in[6];
  const float* Wl2  = (const float*)d_in[7];
  const float* Wr2  = (const float*)d_in[8];
  const float* att2 = (const float*)d_in[9];
  const float* b2   = (const float*)d_in[10];
  const float* Wc   = (const float*)d_in[11];
  const float* bc   = (const float*)d_in[12];

  const int N = in_sizes[0] / 128;
  const int E = in_sizes[1] / 2;

  float* outp   = (float*)d_out;
  float* logits = outp;                    // N*16
  float* hout   = outp + (size_t)N * 16;   // N*128 (h1 staging, then h2)

  char* ws = (char*)d_ws;
  float* xl = (float*)ws;        ws += (size_t)N * 128 * 4;
  float* xr = (float*)ws;        ws += (size_t)N * 128 * 4;
  int* cnt       = (int*)ws;     ws += (size_t)N * 4;
  int* row_start = (int*)ws;     ws += (size_t)(N + 1) * 4;
  int* wpos      = (int*)ws;     ws += (size_t)N * 4;
  int* csr       = (int*)ws;     ws += (size_t)E * 4;

  const int* esrc = ei;
  const int* edst = ei + E;

  int gN = (N + 255) / 256, gE = (E + 255) / 256;
  int gGemm = (N + 127) / 128;
  int gAttn = (N + 3) / 4;

  // CSR build
  zero_i32<<<gN, 256, 0, stream>>>(cnt, N);
  count_kernel<<<gE, 256, 0, stream>>>(edst, cnt, E);
  scan_kernel<<<1, 1024, 0, stream>>>(cnt, row_start, wpos, N);
  scatter_kernel<<<gE, 256, 0, stream>>>(esrc, edst, wpos, csr, E);

  // layer 1
  gemm_dual<<<gGemm, 256, 0, stream>>>(x, Wl1, Wr1, xl, xr, N);
  gat_attn<<<gAttn, 256, 0, stream>>>(xl, xr, row_start, csr, att1, b1, hout, N);

  // layer 2 (h1 staged in hout; overwritten below)
  gemm_dual<<<gGemm, 256, 0, stream>>>(hout, Wl2, Wr2, xl, xr, N);
  gat_attn<<<gAttn, 256, 0, stream>>>(xl, xr, row_start, csr, att2, b2, hout, N);

  // classifier
  classifier_kernel<<<(N * 16 + 255) / 256, 256, 0, stream>>>(hout, Wc, bc, logits, N);
}

// Round 3
// 542.426 us; speedup vs baseline: 1.2356x; 1.2356x over previous
//
#include <hip/hip_runtime.h>

// ---------------------------------------------------------------------------
// GATv2 x2 + classifier. N=50000, E=800000, IN=128, HEADS=4, HID=32, OUT=16.
// R3: GEMMs via MFMA split-bf16 (3-term Ah*Bh + Ah*Bl + Al*Bh, fp32 acc).
//   - dual GEMM as C[N x 256] = A[N x 128] @ [Wl|Wr], block 128x64, 4 waves,
//     grid 391x4 = 1564 blocks. W staged transposed [col][k] for b128 B-frags.
//   - x converted once to bf16 hi/lo; layer-1 attn epilogue emits h1 as
//     bf16 hi/lo directly (fp32 h1 never materialized).
//   - attention unchanged from R2 (4-state online softmax).
// ---------------------------------------------------------------------------

#define LOG2E 1.4426950408889634f

typedef short bf16x8 __attribute__((ext_vector_type(8)));
typedef float f32x4 __attribute__((ext_vector_type(4)));

__device__ __forceinline__ unsigned short f2bf(float f) {
  union { float f; unsigned u; } x; x.f = f;
  unsigned r = x.u + 0x7fffu + ((x.u >> 16) & 1u);
  return (unsigned short)(r >> 16);
}
__device__ __forceinline__ float bf2f(unsigned short h) {
  union { unsigned u; float f; } x; x.u = ((unsigned)h) << 16;
  return x.f;
}

// ------------------------------ CSR build ----------------------------------

__global__ __launch_bounds__(256) void zero_i32(int* __restrict__ p, int n) {
  int i = blockIdx.x * 256 + threadIdx.x;
  if (i < n) p[i] = 0;
}

__global__ __launch_bounds__(256) void count_kernel(const int* __restrict__ dst,
                                                    int* __restrict__ cnt, int E) {
  int i = blockIdx.x * 256 + threadIdx.x;
  if (i < E) atomicAdd(&cnt[dst[i]], 1);
}

__global__ __launch_bounds__(1024) void scan_kernel(const int* __restrict__ cnt,
                                                    int* __restrict__ row_start,
                                                    int* __restrict__ wpos, int n) {
  __shared__ int s[1024];
  int t = threadIdx.x;
  int CH = (n + 1023) >> 10;
  int base = t * CH;
  int lim = min(base + CH, n);
  int sum = 0;
  for (int i = base; i < lim; ++i) sum += cnt[i];
  s[t] = sum;
  __syncthreads();
  for (int off = 1; off < 1024; off <<= 1) {
    int v = (t >= off) ? s[t - off] : 0;
    __syncthreads();
    s[t] += v;
    __syncthreads();
  }
  int run = s[t] - sum;
  for (int i = base; i < lim; ++i) {
    row_start[i] = run;
    wpos[i] = run;
    run += cnt[i];
  }
  if (t == 1023) row_start[n] = s[1023];
}

__global__ __launch_bounds__(256) void scatter_kernel(const int* __restrict__ src,
                                                      const int* __restrict__ dst,
                                                      int* __restrict__ wpos,
                                                      int* __restrict__ csr, int E) {
  int i = blockIdx.x * 256 + threadIdx.x;
  if (i < E) {
    int d = dst[i];
    int p = atomicAdd(&wpos[d], 1);
    csr[p] = src[i];
  }
}

// --------------------------- bf16 split converts ---------------------------

// in: n4 float4's -> hi/lo bf16 (as ushort4)
__global__ __launch_bounds__(256) void convert_split(const float* __restrict__ in,
                                                     unsigned short* __restrict__ hi,
                                                     unsigned short* __restrict__ lo,
                                                     int n4) {
  int i = blockIdx.x * 256 + threadIdx.x;
  if (i >= n4) return;
  float4 v = ((const float4*)in)[i];
  ushort4 h, l;
  h.x = f2bf(v.x); l.x = f2bf(v.x - bf2f(h.x));
  h.y = f2bf(v.y); l.y = f2bf(v.y - bf2f(h.y));
  h.z = f2bf(v.z); l.z = f2bf(v.z - bf2f(h.z));
  h.w = f2bf(v.w); l.w = f2bf(v.w - bf2f(h.w));
  ((ushort4*)hi)[i] = h;
  ((ushort4*)lo)[i] = l;
}

// Wl,Wr [128 x 128] fp32 -> BT hi/lo [256 cols][128 k] bf16 (transposed)
__global__ __launch_bounds__(256) void convert_W(const float* __restrict__ Wl,
                                                 const float* __restrict__ Wr,
                                                 unsigned short* __restrict__ BTh,
                                                 unsigned short* __restrict__ BTl) {
  int idx = blockIdx.x * 256 + threadIdx.x;  // 0..32767
  int col = idx >> 7, k = idx & 127;
  float v = (col < 128) ? Wl[k * 128 + col] : Wr[k * 128 + (col - 128)];
  unsigned short h = f2bf(v);
  BTh[idx] = h;
  BTl[idx] = f2bf(v - bf2f(h));
}

// ------------------------------ MFMA GEMM ----------------------------------
// C[N x 256] = A[N x 128] @ W[128 x 256], split-bf16 3-term.
// grid (ceil(N/128), 4); block 256 = 4 waves; wave tile 64 rows x 32 cols.
// cols 0-127 -> Cl, 128-255 -> Cr (each block entirely in one half).
__global__ __launch_bounds__(256) void gemm_mfma(
    const unsigned short* __restrict__ Ah, const unsigned short* __restrict__ Al,
    const unsigned short* __restrict__ BTh, const unsigned short* __restrict__ BTl,
    float* __restrict__ Cl, float* __restrict__ Cr, int nrows) {
  __shared__ unsigned short sAh[128 * 32], sAl[128 * 32];
  __shared__ unsigned short sBh[64 * 32], sBl[64 * 32];
  int tid = threadIdx.x;
  int wave = tid >> 6, lane = tid & 63;
  int rowBase = blockIdx.x * 128;
  int colBase = blockIdx.y * 64;
  int rowHalf = (wave >> 1) * 64;
  int colHalf = (wave & 1) * 32;
  int l15 = lane & 15, quad = lane >> 4;

  f32x4 acc[4][2];
#pragma unroll
  for (int m = 0; m < 4; ++m)
#pragma unroll
    for (int n = 0; n < 2; ++n) acc[m][n] = (f32x4){0.f, 0.f, 0.f, 0.f};

  for (int kc = 0; kc < 4; ++kc) {
    // stage A: 128 rows x 32 k, hi+lo. 512 x 16B segs per buffer.
#pragma unroll
    for (int i = 0; i < 2; ++i) {
      int idx = tid + i * 256;  // 0..511
      int row = idx >> 2, seg = idx & 3;
      int gr = rowBase + row;
      uint4 vh = make_uint4(0, 0, 0, 0), vl = make_uint4(0, 0, 0, 0);
      if (gr < nrows) {
        vh = *(const uint4*)&Ah[(size_t)gr * 128 + kc * 32 + seg * 8];
        vl = *(const uint4*)&Al[(size_t)gr * 128 + kc * 32 + seg * 8];
      }
      *(uint4*)&sAh[row * 32 + seg * 8] = vh;
      *(uint4*)&sAl[row * 32 + seg * 8] = vl;
    }
    // stage B: 64 cols x 32 k, hi+lo. 256 x 16B segs per buffer.
    {
      int col = tid >> 2, seg = tid & 3;
      *(uint4*)&sBh[col * 32 + seg * 8] =
          *(const uint4*)&BTh[(size_t)(colBase + col) * 128 + kc * 32 + seg * 8];
      *(uint4*)&sBl[col * 32 + seg * 8] =
          *(const uint4*)&BTl[(size_t)(colBase + col) * 128 + kc * 32 + seg * 8];
    }
    __syncthreads();

    bf16x8 afh[4], afl[4], bfh[2], bfl[2];
#pragma unroll
    for (int m = 0; m < 4; ++m) {
      int r = rowHalf + m * 16 + l15;
      afh[m] = *(const bf16x8*)&sAh[r * 32 + quad * 8];
      afl[m] = *(const bf16x8*)&sAl[r * 32 + quad * 8];
    }
#pragma unroll
    for (int n = 0; n < 2; ++n) {
      int cc = colHalf + n * 16 + l15;
      bfh[n] = *(const bf16x8*)&sBh[cc * 32 + quad * 8];
      bfl[n] = *(const bf16x8*)&sBl[cc * 32 + quad * 8];
    }
#pragma unroll
    for (int m = 0; m < 4; ++m)
#pragma unroll
      for (int n = 0; n < 2; ++n) {
        acc[m][n] = __builtin_amdgcn_mfma_f32_16x16x32_bf16(afh[m], bfh[n], acc[m][n], 0, 0, 0);
        acc[m][n] = __builtin_amdgcn_mfma_f32_16x16x32_bf16(afh[m], bfl[n], acc[m][n], 0, 0, 0);
        acc[m][n] = __builtin_amdgcn_mfma_f32_16x16x32_bf16(afl[m], bfh[n], acc[m][n], 0, 0, 0);
      }
    __syncthreads();
  }

  // epilogue: C/D layout col=lane&15, row=quad*4+reg
  bool isL = (colBase < 128);
  float* __restrict__ C = isL ? Cl : Cr;
  int cb = (isL ? colBase : colBase - 128) + colHalf;
#pragma unroll
  for (int m = 0; m < 4; ++m)
#pragma unroll
    for (int r = 0; r < 4; ++r) {
      int grow = rowBase + rowHalf + m * 16 + quad * 4 + r;
      if (grow < nrows) {
#pragma unroll
        for (int n = 0; n < 2; ++n)
          C[(size_t)grow * 128 + cb + n * 16 + l15] = acc[m][n][r];
      }
    }
}

// ------------------------------ attention ----------------------------------
// One wave per node; lane handles channels (2*lane, 2*lane+1), head = lane/16.
// 4 independent online-softmax states (edge i -> state i%4), merged at end.
// Output: fp32 (ofp) and/or bf16 hi/lo split (oh_hi/oh_lo), null-selectable.
__global__ __launch_bounds__(256) void gat_attn(const float* __restrict__ xl,
                                                const float* __restrict__ xr,
                                                const int* __restrict__ row_start,
                                                const int* __restrict__ csr,
                                                const float* __restrict__ att,
                                                const float* __restrict__ bias,
                                                float* __restrict__ ofp,
                                                unsigned short* __restrict__ oh_hi,
                                                unsigned short* __restrict__ oh_lo,
                                                int n_nodes) {
  int node = blockIdx.x * 4 + (threadIdx.x >> 6);
  if (node >= n_nodes) return;
  int lane = threadIdx.x & 63;
  int c = lane * 2;
  float2 xrd = *(const float2*)&xr[(size_t)node * 128 + c];
  float ax = att[c], ay = att[c + 1];

  float m[4], l[4], sx[4], sy[4];
  {
    float2 xs = *(const float2*)&xl[(size_t)node * 128 + c];
    float t0 = xs.x + xrd.x; t0 = (t0 > 0.f) ? t0 : 0.2f * t0;
    float t1 = xs.y + xrd.y; t1 = (t1 > 0.f) ? t1 : 0.2f * t1;
    float t = t0 * ax + t1 * ay;
    t += __shfl_xor(t, 1); t += __shfl_xor(t, 2);
    t += __shfl_xor(t, 4); t += __shfl_xor(t, 8);
    m[0] = t * LOG2E; l[0] = 1.f; sx[0] = xs.x; sy[0] = xs.y;
  }
#pragma unroll
  for (int k = 1; k < 4; ++k) { m[k] = -1e30f; l[k] = 0.f; sx[k] = 0.f; sy[k] = 0.f; }

  int beg = row_start[node], end = row_start[node + 1];
  for (int i = beg; i < end; i += 4) {
    int srcs[4];
    float2 xs[4];
    float e[4];
#pragma unroll
    for (int j = 0; j < 4; ++j) srcs[j] = (i + j < end) ? csr[i + j] : node;
#pragma unroll
    for (int j = 0; j < 4; ++j)
      xs[j] = *(const float2*)&xl[(size_t)srcs[j] * 128 + c];
#pragma unroll
    for (int j = 0; j < 4; ++j) {
      float t0 = xs[j].x + xrd.x; t0 = (t0 > 0.f) ? t0 : 0.2f * t0;
      float t1 = xs[j].y + xrd.y; t1 = (t1 > 0.f) ? t1 : 0.2f * t1;
      float t = t0 * ax + t1 * ay;
      t += __shfl_xor(t, 1); t += __shfl_xor(t, 2);
      t += __shfl_xor(t, 4); t += __shfl_xor(t, 8);
      e[j] = (i + j < end) ? t * LOG2E : -2e30f;
    }
#pragma unroll
    for (int j = 0; j < 4; ++j) {
      float nm = fmaxf(m[j], e[j]);
      float s = exp2f(m[j] - nm);
      float p = exp2f(e[j] - nm);
      l[j] = l[j] * s + p;
      sx[j] = sx[j] * s + p * xs[j].x;
      sy[j] = sy[j] * s + p * xs[j].y;
      m[j] = nm;
    }
  }
#pragma unroll
  for (int step = 0; step < 3; ++step) {
    int a = (step == 0) ? 0 : (step == 1) ? 2 : 0;
    int b = (step == 0) ? 1 : (step == 1) ? 3 : 2;
    float nm = fmaxf(m[a], m[b]);
    float s0 = exp2f(m[a] - nm), s1 = exp2f(m[b] - nm);
    l[a] = l[a] * s0 + l[b] * s1;
    sx[a] = sx[a] * s0 + sx[b] * s1;
    sy[a] = sy[a] * s0 + sy[b] * s1;
    m[a] = nm;
  }
  float inv = 1.f / (l[0] + 1e-16f);
  float ox = sx[0] * inv + bias[c];
  float oy = sy[0] * inv + bias[c + 1];
  ox = (ox > 0.f) ? ox : 0.01f * ox;
  oy = (oy > 0.f) ? oy : 0.01f * oy;
  if (ofp) *(float2*)&ofp[(size_t)node * 128 + c] = make_float2(ox, oy);
  if (oh_hi) {
    unsigned short hx = f2bf(ox), hy = f2bf(oy);
    unsigned short lx = f2bf(ox - bf2f(hx)), ly = f2bf(oy - bf2f(hy));
    *(ushort2*)&oh_hi[(size_t)node * 128 + c] = make_ushort2(hx, hy);
    *(ushort2*)&oh_lo[(size_t)node * 128 + c] = make_ushort2(lx, ly);
  }
}

__global__ __launch_bounds__(256) void classifier_kernel(const float* __restrict__ h,
                                                         const float* __restrict__ Wc,
                                                         const float* __restrict__ bc,
                                                         float* __restrict__ logits,
                                                         int n) {
  int idx = blockIdx.x * 256 + threadIdx.x;
  if (idx >= n * 16) return;
  int node = idx >> 4, o = idx & 15;
  float acc = bc[o];
  const float* hrow = &h[(size_t)node * 128];
#pragma unroll
  for (int cc = 0; cc < 128; ++cc) acc = fmaf(hrow[cc], Wc[cc * 16 + o], acc);
  logits[idx] = acc;
}

// ---------------------------------------------------------------------------

extern "C" void kernel_launch(void* const* d_in, const int* in_sizes, int n_in,
                              void* d_out, int out_size, void* d_ws, size_t ws_size,
                              hipStream_t stream) {
  const float* x    = (const float*)d_in[0];
  const int*   ei   = (const int*)d_in[1];
  const float* Wl1  = (const float*)d_in[3];
  const float* Wr1  = (const float*)d_in[4];
  const float* att1 = (const float*)d_in[5];
  const float* b1   = (const float*)d_in[6];
  const float* Wl2  = (const float*)d_in[7];
  const float* Wr2  = (const float*)d_in[8];
  const float* att2 = (const float*)d_in[9];
  const float* b2   = (const float*)d_in[10];
  const float* Wc   = (const float*)d_in[11];
  const float* bc   = (const float*)d_in[12];

  const int N = in_sizes[0] / 128;
  const int E = in_sizes[1] / 2;

  float* outp   = (float*)d_out;
  float* logits = outp;                   // N*16 fp32
  float* hout   = outp + (size_t)N * 16;  // N*128 fp32 region
  // region reuse timeline: [xh|xlo bf16] -> [h1h|h1l bf16] -> h2 fp32
  unsigned short* regionA = (unsigned short*)hout;
  unsigned short* regionB = regionA + (size_t)N * 128;

  char* ws = (char*)d_ws;
  float* xlbuf = (float*)ws;               ws += (size_t)N * 128 * 4;
  float* xrbuf = (float*)ws;               ws += (size_t)N * 128 * 4;
  unsigned short* WT1h = (unsigned short*)ws; ws += 256 * 128 * 2;
  unsigned short* WT1l = (unsigned short*)ws; ws += 256 * 128 * 2;
  unsigned short* WT2h = (unsigned short*)ws; ws += 256 * 128 * 2;
  unsigned short* WT2l = (unsigned short*)ws; ws += 256 * 128 * 2;
  int* cnt       = (int*)ws;               ws += (size_t)N * 4;
  int* row_start = (int*)ws;               ws += (size_t)(N + 1) * 4;
  int* wpos      = (int*)ws;               ws += (size_t)N * 4;
  int* csr       = (int*)ws;               ws += (size_t)E * 4;

  const int* esrc = ei;
  const int* edst = ei + E;

  int gN = (N + 255) / 256, gE = (E + 255) / 256;
  dim3 gGemm((N + 127) / 128, 4);
  int gAttn = (N + 3) / 4;
  int gConv = (N * 128 / 4 + 255) / 256;

  // CSR build
  zero_i32<<<gN, 256, 0, stream>>>(cnt, N);
  count_kernel<<<gE, 256, 0, stream>>>(edst, cnt, E);
  scan_kernel<<<1, 1024, 0, stream>>>(cnt, row_start, wpos, N);
  scatter_kernel<<<gE, 256, 0, stream>>>(esrc, edst, wpos, csr, E);

  // weight + input conversions
  convert_W<<<128, 256, 0, stream>>>(Wl1, Wr1, WT1h, WT1l);
  convert_W<<<128, 256, 0, stream>>>(Wl2, Wr2, WT2h, WT2l);
  convert_split<<<gConv, 256, 0, stream>>>(x, regionA, regionB, N * 128 / 4);

  // layer 1
  gemm_mfma<<<gGemm, 256, 0, stream>>>(regionA, regionB, WT1h, WT1l, xlbuf, xrbuf, N);
  gat_attn<<<gAttn, 256, 0, stream>>>(xlbuf, xrbuf, row_start, csr, att1, b1,
                                      nullptr, regionA, regionB, N);

  // layer 2
  gemm_mfma<<<gGemm, 256, 0, stream>>>(regionA, regionB, WT2h, WT2l, xlbuf, xrbuf, N);
  gat_attn<<<gAttn, 256, 0, stream>>>(xlbuf, xrbuf, row_start, csr, att2, b2,
                                      hout, nullptr, nullptr, N);

  // classifier
  classifier_kernel<<<(N * 16 + 255) / 256, 256, 0, stream>>>(hout, Wc, bc, logits, N);
}

// Round 4
// 437.202 us; speedup vs baseline: 1.5330x; 1.2407x over previous
//
#include <hip/hip_runtime.h>

// ---------------------------------------------------------------------------
// GATv2 x2 + classifier. N=50000, E=800000, IN=128, HEADS=4, HID=32, OUT=16.
// R4: (a) hierarchical scan (the single-block scan was 111us = 20% of total);
//     (b) gat_attn v3: 32 lanes/edge (float4/lane), 2 edges per wave in
//     parallel, 4 softmax states per half -> 8 gathers in flight.
// GEMM (MFMA split-bf16) unchanged from R3.
// ---------------------------------------------------------------------------

#define LOG2E 1.4426950408889634f

typedef short bf16x8 __attribute__((ext_vector_type(8)));
typedef float f32x4 __attribute__((ext_vector_type(4)));

__device__ __forceinline__ unsigned short f2bf(float f) {
  union { float f; unsigned u; } x; x.f = f;
  unsigned r = x.u + 0x7fffu + ((x.u >> 16) & 1u);
  return (unsigned short)(r >> 16);
}
__device__ __forceinline__ float bf2f(unsigned short h) {
  union { unsigned u; float f; } x; x.u = ((unsigned)h) << 16;
  return x.f;
}

// ------------------------------ CSR build ----------------------------------

__global__ __launch_bounds__(256) void zero_i32(int* __restrict__ p, int n) {
  int i = blockIdx.x * 256 + threadIdx.x;
  if (i < n) p[i] = 0;
}

__global__ __launch_bounds__(256) void count_kernel(const int* __restrict__ dst,
                                                    int* __restrict__ cnt, int E) {
  int i = blockIdx.x * 256 + threadIdx.x;
  if (i < E) atomicAdd(&cnt[dst[i]], 1);
}

// stage 1: per-block exclusive scan of 256 counts; block total -> bsum
__global__ __launch_bounds__(256) void scan_blk(const int* __restrict__ cnt,
                                                int* __restrict__ excl,
                                                int* __restrict__ bsum, int n) {
  __shared__ int s[256];
  int t = threadIdx.x, i = blockIdx.x * 256 + t;
  int v = (i < n) ? cnt[i] : 0;
  s[t] = v;
  __syncthreads();
#pragma unroll
  for (int off = 1; off < 256; off <<= 1) {
    int u = (t >= off) ? s[t - off] : 0;
    __syncthreads();
    s[t] += u;
    __syncthreads();
  }
  if (i < n) excl[i] = s[t] - v;
  if (t == 255) bsum[blockIdx.x] = s[255];
}

// stage 2: single block scans block sums (nb <= 256); writes row_start[n]=total
__global__ __launch_bounds__(256) void scan_bsum(int* __restrict__ bsum, int nb,
                                                 int* __restrict__ row_start, int n) {
  __shared__ int s[256];
  int t = threadIdx.x;
  int v = (t < nb) ? bsum[t] : 0;
  s[t] = v;
  __syncthreads();
#pragma unroll
  for (int off = 1; off < 256; off <<= 1) {
    int u = (t >= off) ? s[t - off] : 0;
    __syncthreads();
    s[t] += u;
    __syncthreads();
  }
  if (t < nb) bsum[t] = s[t] - v;  // exclusive
  if (t == 255) row_start[n] = s[255];
}

// stage 3: add block offsets; also init wpos
__global__ __launch_bounds__(256) void scan_add(int* __restrict__ row_start,
                                                const int* __restrict__ bsum,
                                                int* __restrict__ wpos, int n) {
  int i = blockIdx.x * 256 + threadIdx.x;
  if (i < n) {
    int r = row_start[i] + bsum[blockIdx.x];
    row_start[i] = r;
    wpos[i] = r;
  }
}

__global__ __launch_bounds__(256) void scatter_kernel(const int* __restrict__ src,
                                                      const int* __restrict__ dst,
                                                      int* __restrict__ wpos,
                                                      int* __restrict__ csr, int E) {
  int i = blockIdx.x * 256 + threadIdx.x;
  if (i < E) {
    int d = dst[i];
    int p = atomicAdd(&wpos[d], 1);
    csr[p] = src[i];
  }
}

// --------------------------- bf16 split converts ---------------------------

__global__ __launch_bounds__(256) void convert_split(const float* __restrict__ in,
                                                     unsigned short* __restrict__ hi,
                                                     unsigned short* __restrict__ lo,
                                                     int n4) {
  int i = blockIdx.x * 256 + threadIdx.x;
  if (i >= n4) return;
  float4 v = ((const float4*)in)[i];
  ushort4 h, l;
  h.x = f2bf(v.x); l.x = f2bf(v.x - bf2f(h.x));
  h.y = f2bf(v.y); l.y = f2bf(v.y - bf2f(h.y));
  h.z = f2bf(v.z); l.z = f2bf(v.z - bf2f(h.z));
  h.w = f2bf(v.w); l.w = f2bf(v.w - bf2f(h.w));
  ((ushort4*)hi)[i] = h;
  ((ushort4*)lo)[i] = l;
}

__global__ __launch_bounds__(256) void convert_W(const float* __restrict__ Wl,
                                                 const float* __restrict__ Wr,
                                                 unsigned short* __restrict__ BTh,
                                                 unsigned short* __restrict__ BTl) {
  int idx = blockIdx.x * 256 + threadIdx.x;  // 0..32767
  int col = idx >> 7, k = idx & 127;
  float v = (col < 128) ? Wl[k * 128 + col] : Wr[k * 128 + (col - 128)];
  unsigned short h = f2bf(v);
  BTh[idx] = h;
  BTl[idx] = f2bf(v - bf2f(h));
}

// ------------------------------ MFMA GEMM ----------------------------------
// C[N x 256] = A[N x 128] @ W[128 x 256], split-bf16 3-term. (as R3)
__global__ __launch_bounds__(256) void gemm_mfma(
    const unsigned short* __restrict__ Ah, const unsigned short* __restrict__ Al,
    const unsigned short* __restrict__ BTh, const unsigned short* __restrict__ BTl,
    float* __restrict__ Cl, float* __restrict__ Cr, int nrows) {
  __shared__ unsigned short sAh[128 * 32], sAl[128 * 32];
  __shared__ unsigned short sBh[64 * 32], sBl[64 * 32];
  int tid = threadIdx.x;
  int wave = tid >> 6, lane = tid & 63;
  int rowBase = blockIdx.x * 128;
  int colBase = blockIdx.y * 64;
  int rowHalf = (wave >> 1) * 64;
  int colHalf = (wave & 1) * 32;
  int l15 = lane & 15, quad = lane >> 4;

  f32x4 acc[4][2];
#pragma unroll
  for (int m = 0; m < 4; ++m)
#pragma unroll
    for (int n = 0; n < 2; ++n) acc[m][n] = (f32x4){0.f, 0.f, 0.f, 0.f};

  for (int kc = 0; kc < 4; ++kc) {
#pragma unroll
    for (int i = 0; i < 2; ++i) {
      int idx = tid + i * 256;
      int row = idx >> 2, seg = idx & 3;
      int gr = rowBase + row;
      uint4 vh = make_uint4(0, 0, 0, 0), vl = make_uint4(0, 0, 0, 0);
      if (gr < nrows) {
        vh = *(const uint4*)&Ah[(size_t)gr * 128 + kc * 32 + seg * 8];
        vl = *(const uint4*)&Al[(size_t)gr * 128 + kc * 32 + seg * 8];
      }
      *(uint4*)&sAh[row * 32 + seg * 8] = vh;
      *(uint4*)&sAl[row * 32 + seg * 8] = vl;
    }
    {
      int col = tid >> 2, seg = tid & 3;
      *(uint4*)&sBh[col * 32 + seg * 8] =
          *(const uint4*)&BTh[(size_t)(colBase + col) * 128 + kc * 32 + seg * 8];
      *(uint4*)&sBl[col * 32 + seg * 8] =
          *(const uint4*)&BTl[(size_t)(colBase + col) * 128 + kc * 32 + seg * 8];
    }
    __syncthreads();

    bf16x8 afh[4], afl[4], bfh[2], bfl[2];
#pragma unroll
    for (int m = 0; m < 4; ++m) {
      int r = rowHalf + m * 16 + l15;
      afh[m] = *(const bf16x8*)&sAh[r * 32 + quad * 8];
      afl[m] = *(const bf16x8*)&sAl[r * 32 + quad * 8];
    }
#pragma unroll
    for (int n = 0; n < 2; ++n) {
      int cc = colHalf + n * 16 + l15;
      bfh[n] = *(const bf16x8*)&sBh[cc * 32 + quad * 8];
      bfl[n] = *(const bf16x8*)&sBl[cc * 32 + quad * 8];
    }
#pragma unroll
    for (int m = 0; m < 4; ++m)
#pragma unroll
      for (int n = 0; n < 2; ++n) {
        acc[m][n] = __builtin_amdgcn_mfma_f32_16x16x32_bf16(afh[m], bfh[n], acc[m][n], 0, 0, 0);
        acc[m][n] = __builtin_amdgcn_mfma_f32_16x16x32_bf16(afh[m], bfl[n], acc[m][n], 0, 0, 0);
        acc[m][n] = __builtin_amdgcn_mfma_f32_16x16x32_bf16(afl[m], bfh[n], acc[m][n], 0, 0, 0);
      }
    __syncthreads();
  }

  bool isL = (colBase < 128);
  float* __restrict__ C = isL ? Cl : Cr;
  int cb = (isL ? colBase : colBase - 128) + colHalf;
#pragma unroll
  for (int m = 0; m < 4; ++m)
#pragma unroll
    for (int r = 0; r < 4; ++r) {
      int grow = rowBase + rowHalf + m * 16 + quad * 4 + r;
      if (grow < nrows) {
#pragma unroll
        for (int n = 0; n < 2; ++n)
          C[(size_t)grow * 128 + cb + n * 16 + l15] = acc[m][n][r];
      }
    }
}

// ------------------------------ attention ----------------------------------
// One wave per node. 32 lanes per edge (float4 of channels per lane);
// half = lane>>5 processes even/odd edges; 4 softmax states per half
// (8 gathers in flight). Head = 8-lane group -> 3 shfl_xor reduction.
// Halves merged at the end via shfl_xor(32).
__device__ __forceinline__ float4 leaky02(float4 v) {
  v.x = (v.x > 0.f) ? v.x : 0.2f * v.x;
  v.y = (v.y > 0.f) ? v.y : 0.2f * v.y;
  v.z = (v.z > 0.f) ? v.z : 0.2f * v.z;
  v.w = (v.w > 0.f) ? v.w : 0.2f * v.w;
  return v;
}

__global__ __launch_bounds__(256) void gat_attn(const float* __restrict__ xl,
                                                const float* __restrict__ xr,
                                                const int* __restrict__ row_start,
                                                const int* __restrict__ csr,
                                                const float* __restrict__ att,
                                                const float* __restrict__ bias,
                                                float* __restrict__ ofp,
                                                unsigned short* __restrict__ oh_hi,
                                                unsigned short* __restrict__ oh_lo,
                                                int n_nodes) {
  int node = blockIdx.x * 4 + (threadIdx.x >> 6);
  if (node >= n_nodes) return;
  int lane = threadIdx.x & 63;
  int half = lane >> 5;
  int c0 = (lane & 31) * 4;

  float4 xrd = *(const float4*)&xr[(size_t)node * 128 + c0];
  float4 a4 = *(const float4*)&att[c0];

  float m[4], l[4];
  float4 acc[4];
#pragma unroll
  for (int j = 0; j < 4; ++j) {
    m[j] = -1e30f; l[j] = 0.f;
    acc[j] = make_float4(0.f, 0.f, 0.f, 0.f);
  }

  // self loop -> half 0, state 0 (both halves compute; half 1 discards)
  {
    float4 xs = *(const float4*)&xl[(size_t)node * 128 + c0];
    float4 t4 = leaky02(make_float4(xs.x + xrd.x, xs.y + xrd.y, xs.z + xrd.z, xs.w + xrd.w));
    float t = t4.x * a4.x + t4.y * a4.y + t4.z * a4.z + t4.w * a4.w;
    t += __shfl_xor(t, 1); t += __shfl_xor(t, 2); t += __shfl_xor(t, 4);
    if (half == 0) { m[0] = t * LOG2E; l[0] = 1.f; acc[0] = xs; }
  }

  int beg = row_start[node], end = row_start[node + 1];
  for (int base = beg; base < end; base += 8) {
    int idxj[4], srcs[4];
    float4 xs[4];
    float e[4];
#pragma unroll
    for (int j = 0; j < 4; ++j) {
      idxj[j] = base + 2 * j + half;
      srcs[j] = (idxj[j] < end) ? csr[idxj[j]] : node;
    }
#pragma unroll
    for (int j = 0; j < 4; ++j)
      xs[j] = *(const float4*)&xl[(size_t)srcs[j] * 128 + c0];
#pragma unroll
    for (int j = 0; j < 4; ++j) {
      float4 t4 = leaky02(make_float4(xs[j].x + xrd.x, xs[j].y + xrd.y,
                                      xs[j].z + xrd.z, xs[j].w + xrd.w));
      float t = t4.x * a4.x + t4.y * a4.y + t4.z * a4.z + t4.w * a4.w;
      t += __shfl_xor(t, 1); t += __shfl_xor(t, 2); t += __shfl_xor(t, 4);
      e[j] = (idxj[j] < end) ? t * LOG2E : -2e30f;
    }
#pragma unroll
    for (int j = 0; j < 4; ++j) {
      float nm = fmaxf(m[j], e[j]);
      float s = exp2f(m[j] - nm);
      float p = exp2f(e[j] - nm);
      l[j] = l[j] * s + p;
      acc[j].x = acc[j].x * s + p * xs[j].x;
      acc[j].y = acc[j].y * s + p * xs[j].y;
      acc[j].z = acc[j].z * s + p * xs[j].z;
      acc[j].w = acc[j].w * s + p * xs[j].w;
      m[j] = nm;
    }
  }

  // merge 4 states within half: 1->0, 3->2, 2->0
#pragma unroll
  for (int step = 0; step < 3; ++step) {
    int a = (step == 0) ? 0 : (step == 1) ? 2 : 0;
    int b = (step == 0) ? 1 : (step == 1) ? 3 : 2;
    float nm = fmaxf(m[a], m[b]);
    float s0 = exp2f(m[a] - nm), s1 = exp2f(m[b] - nm);
    l[a] = l[a] * s0 + l[b] * s1;
    acc[a].x = acc[a].x * s0 + acc[b].x * s1;
    acc[a].y = acc[a].y * s0 + acc[b].y * s1;
    acc[a].z = acc[a].z * s0 + acc[b].z * s1;
    acc[a].w = acc[a].w * s0 + acc[b].w * s1;
    m[a] = nm;
  }
  // merge across halves via shfl_xor 32
  {
    float om = __shfl_xor(m[0], 32);
    float ol = __shfl_xor(l[0], 32);
    float ox = __shfl_xor(acc[0].x, 32);
    float oy = __shfl_xor(acc[0].y, 32);
    float oz = __shfl_xor(acc[0].z, 32);
    float ow = __shfl_xor(acc[0].w, 32);
    float nm = fmaxf(m[0], om);
    float s0 = exp2f(m[0] - nm), s1 = exp2f(om - nm);
    l[0] = l[0] * s0 + ol * s1;
    acc[0].x = acc[0].x * s0 + ox * s1;
    acc[0].y = acc[0].y * s0 + oy * s1;
    acc[0].z = acc[0].z * s0 + oz * s1;
    acc[0].w = acc[0].w * s0 + ow * s1;
  }
  if (half == 0) {
    float4 b4 = *(const float4*)&bias[c0];
    float inv = 1.f / (l[0] + 1e-16f);
    float4 o;
    o.x = acc[0].x * inv + b4.x;
    o.y = acc[0].y * inv + b4.y;
    o.z = acc[0].z * inv + b4.z;
    o.w = acc[0].w * inv + b4.w;
    o.x = (o.x > 0.f) ? o.x : 0.01f * o.x;
    o.y = (o.y > 0.f) ? o.y : 0.01f * o.y;
    o.z = (o.z > 0.f) ? o.z : 0.01f * o.z;
    o.w = (o.w > 0.f) ? o.w : 0.01f * o.w;
    if (ofp) *(float4*)&ofp[(size_t)node * 128 + c0] = o;
    if (oh_hi) {
      ushort4 h, lo;
      h.x = f2bf(o.x); lo.x = f2bf(o.x - bf2f(h.x));
      h.y = f2bf(o.y); lo.y = f2bf(o.y - bf2f(h.y));
      h.z = f2bf(o.z); lo.z = f2bf(o.z - bf2f(h.z));
      h.w = f2bf(o.w); lo.w = f2bf(o.w - bf2f(h.w));
      *(ushort4*)&oh_hi[(size_t)node * 128 + c0] = h;
      *(ushort4*)&oh_lo[(size_t)node * 128 + c0] = lo;
    }
  }
}

__global__ __launch_bounds__(256) void classifier_kernel(const float* __restrict__ h,
                                                         const float* __restrict__ Wc,
                                                         const float* __restrict__ bc,
                                                         float* __restrict__ logits,
                                                         int n) {
  int idx = blockIdx.x * 256 + threadIdx.x;
  if (idx >= n * 16) return;
  int node = idx >> 4, o = idx & 15;
  float acc = bc[o];
  const float* hrow = &h[(size_t)node * 128];
#pragma unroll
  for (int cc = 0; cc < 128; ++cc) acc = fmaf(hrow[cc], Wc[cc * 16 + o], acc);
  logits[idx] = acc;
}

// ---------------------------------------------------------------------------

extern "C" void kernel_launch(void* const* d_in, const int* in_sizes, int n_in,
                              void* d_out, int out_size, void* d_ws, size_t ws_size,
                              hipStream_t stream) {
  const float* x    = (const float*)d_in[0];
  const int*   ei   = (const int*)d_in[1];
  const float* Wl1  = (const float*)d_in[3];
  const float* Wr1  = (const float*)d_in[4];
  const float* att1 = (const float*)d_in[5];
  const float* b1   = (const float*)d_in[6];
  const float* Wl2  = (const float*)d_in[7];
  const float* Wr2  = (const float*)d_in[8];
  const float* att2 = (const float*)d_in[9];
  const float* b2   = (const float*)d_in[10];
  const float* Wc   = (const float*)d_in[11];
  const float* bc   = (const float*)d_in[12];

  const int N = in_sizes[0] / 128;
  const int E = in_sizes[1] / 2;

  float* outp   = (float*)d_out;
  float* logits = outp;                   // N*16 fp32
  float* hout   = outp + (size_t)N * 16;  // N*128 fp32 region
  unsigned short* regionA = (unsigned short*)hout;
  unsigned short* regionB = regionA + (size_t)N * 128;

  char* ws = (char*)d_ws;
  float* xlbuf = (float*)ws;               ws += (size_t)N * 128 * 4;
  float* xrbuf = (float*)ws;               ws += (size_t)N * 128 * 4;
  unsigned short* WT1h = (unsigned short*)ws; ws += 256 * 128 * 2;
  unsigned short* WT1l = (unsigned short*)ws; ws += 256 * 128 * 2;
  unsigned short* WT2h = (unsigned short*)ws; ws += 256 * 128 * 2;
  unsigned short* WT2l = (unsigned short*)ws; ws += 256 * 128 * 2;
  int* cnt       = (int*)ws;               ws += (size_t)N * 4;
  int* row_start = (int*)ws;               ws += (size_t)(N + 1) * 4;
  int* wpos      = (int*)ws;               ws += (size_t)N * 4;
  int* bsum      = (int*)ws;               ws += 256 * 4;
  int* csr       = (int*)ws;               ws += (size_t)E * 4;

  const int* esrc = ei;
  const int* edst = ei + E;

  int gN = (N + 255) / 256, gE = (E + 255) / 256;
  dim3 gGemm((N + 127) / 128, 4);
  int gAttn = (N + 3) / 4;
  int gConv = (N * 128 / 4 + 255) / 256;

  // CSR build (hierarchical scan)
  zero_i32<<<gN, 256, 0, stream>>>(cnt, N);
  count_kernel<<<gE, 256, 0, stream>>>(edst, cnt, E);
  scan_blk<<<gN, 256, 0, stream>>>(cnt, row_start, bsum, N);
  scan_bsum<<<1, 256, 0, stream>>>(bsum, gN, row_start, N);
  scan_add<<<gN, 256, 0, stream>>>(row_start, bsum, wpos, N);
  scatter_kernel<<<gE, 256, 0, stream>>>(esrc, edst, wpos, csr, E);

  // weight + input conversions
  convert_W<<<128, 256, 0, stream>>>(Wl1, Wr1, WT1h, WT1l);
  convert_W<<<128, 256, 0, stream>>>(Wl2, Wr2, WT2h, WT2l);
  convert_split<<<gConv, 256, 0, stream>>>(x, regionA, regionB, N * 128 / 4);

  // layer 1
  gemm_mfma<<<gGemm, 256, 0, stream>>>(regionA, regionB, WT1h, WT1l, xlbuf, xrbuf, N);
  gat_attn<<<gAttn, 256, 0, stream>>>(xlbuf, xrbuf, row_start, csr, att1, b1,
                                      nullptr, regionA, regionB, N);

  // layer 2
  gemm_mfma<<<gGemm, 256, 0, stream>>>(regionA, regionB, WT2h, WT2l, xlbuf, xrbuf, N);
  gat_attn<<<gAttn, 256, 0, stream>>>(xlbuf, xrbuf, row_start, csr, att2, b2,
                                      hout, nullptr, nullptr, N);

  // classifier
  classifier_kernel<<<(N * 16 + 255) / 256, 256, 0, stream>>>(hout, Wc, bc, logits, N);
}

// Round 5
// 388.160 us; speedup vs baseline: 1.7267x; 1.1263x over previous
//
#include <hip/hip_runtime.h>

// ---------------------------------------------------------------------------
// GATv2 x2 + classifier. N=50000, E=800000, IN=128, HEADS=4, HID=32, OUT=16.
// R5: attn VALU diet: leaky folded into dot (0.6t+0.4|t|, |.| is a free VALU
//     modifier; att pre-scaled by log2e), raw-exp softmax (no max tracking --
//     scores are O(10), exp2 overflows only past e~88), unmasked main loop +
//     masked 2-edge tail (kills ~20% padding waste), 32-bit saddr gathers.
//     convert_split fused into layer-1 GEMM staging; classifier rewritten
//     (node/thread, Wc in LDS, float4).
// ---------------------------------------------------------------------------

#define LOG2E 1.4426950408889634f

typedef short bf16x8 __attribute__((ext_vector_type(8)));
typedef float f32x4 __attribute__((ext_vector_type(4)));

__device__ __forceinline__ unsigned short f2bf(float f) {
  union { float f; unsigned u; } x; x.f = f;
  unsigned r = x.u + 0x7fffu + ((x.u >> 16) & 1u);
  return (unsigned short)(r >> 16);
}
__device__ __forceinline__ float bf2f(unsigned short h) {
  union { unsigned u; float f; } x; x.u = ((unsigned)h) << 16;
  return x.f;
}
__device__ __forceinline__ void split4(float4 v, ushort4& h, ushort4& l) {
  h.x = f2bf(v.x); l.x = f2bf(v.x - bf2f(h.x));
  h.y = f2bf(v.y); l.y = f2bf(v.y - bf2f(h.y));
  h.z = f2bf(v.z); l.z = f2bf(v.z - bf2f(h.z));
  h.w = f2bf(v.w); l.w = f2bf(v.w - bf2f(h.w));
}

// ------------------------------ CSR build ----------------------------------

__global__ __launch_bounds__(256) void zero_i32(int* __restrict__ p, int n) {
  int i = blockIdx.x * 256 + threadIdx.x;
  if (i < n) p[i] = 0;
}

__global__ __launch_bounds__(256) void count_kernel(const int* __restrict__ dst,
                                                    int* __restrict__ cnt, int E) {
  int i = blockIdx.x * 256 + threadIdx.x;
  if (i < E) atomicAdd(&cnt[dst[i]], 1);
}

__global__ __launch_bounds__(256) void scan_blk(const int* __restrict__ cnt,
                                                int* __restrict__ excl,
                                                int* __restrict__ bsum, int n) {
  __shared__ int s[256];
  int t = threadIdx.x, i = blockIdx.x * 256 + t;
  int v = (i < n) ? cnt[i] : 0;
  s[t] = v;
  __syncthreads();
#pragma unroll
  for (int off = 1; off < 256; off <<= 1) {
    int u = (t >= off) ? s[t - off] : 0;
    __syncthreads();
    s[t] += u;
    __syncthreads();
  }
  if (i < n) excl[i] = s[t] - v;
  if (t == 255) bsum[blockIdx.x] = s[255];
}

__global__ __launch_bounds__(256) void scan_bsum(int* __restrict__ bsum, int nb,
                                                 int* __restrict__ row_start, int n) {
  __shared__ int s[256];
  int t = threadIdx.x;
  int v = (t < nb) ? bsum[t] : 0;
  s[t] = v;
  __syncthreads();
#pragma unroll
  for (int off = 1; off < 256; off <<= 1) {
    int u = (t >= off) ? s[t - off] : 0;
    __syncthreads();
    s[t] += u;
    __syncthreads();
  }
  if (t < nb) bsum[t] = s[t] - v;
  if (t == 255) row_start[n] = s[255];
}

__global__ __launch_bounds__(256) void scan_add(int* __restrict__ row_start,
                                                const int* __restrict__ bsum,
                                                int* __restrict__ wpos, int n) {
  int i = blockIdx.x * 256 + threadIdx.x;
  if (i < n) {
    int r = row_start[i] + bsum[blockIdx.x];
    row_start[i] = r;
    wpos[i] = r;
  }
}

__global__ __launch_bounds__(256) void scatter_kernel(const int* __restrict__ src,
                                                      const int* __restrict__ dst,
                                                      int* __restrict__ wpos,
                                                      int* __restrict__ csr, int E) {
  int i = blockIdx.x * 256 + threadIdx.x;
  if (i < E) {
    int d = dst[i];
    int p = atomicAdd(&wpos[d], 1);
    csr[p] = src[i];
  }
}

// --------------------------- weight converts -------------------------------

__global__ __launch_bounds__(256) void convert_W(const float* __restrict__ Wl,
                                                 const float* __restrict__ Wr,
                                                 unsigned short* __restrict__ BTh,
                                                 unsigned short* __restrict__ BTl) {
  int idx = blockIdx.x * 256 + threadIdx.x;  // 0..32767
  int col = idx >> 7, k = idx & 127;
  float v = (col < 128) ? Wl[k * 128 + col] : Wr[k * 128 + (col - 128)];
  unsigned short h = f2bf(v);
  BTh[idx] = h;
  BTl[idx] = f2bf(v - bf2f(h));
}

// ------------------------------ MFMA GEMM ----------------------------------
// C[N x 256] = A[N x 128] @ W[128 x 256], split-bf16 3-term.
// FP32IN: A read as fp32 and hi/lo-split inline during LDS staging.
template <bool FP32IN>
__global__ __launch_bounds__(256) void gemm_mfma(
    const float* __restrict__ Af,
    const unsigned short* __restrict__ Ah, const unsigned short* __restrict__ Al,
    const unsigned short* __restrict__ BTh, const unsigned short* __restrict__ BTl,
    float* __restrict__ Cl, float* __restrict__ Cr, int nrows) {
  __shared__ unsigned short sAh[128 * 32], sAl[128 * 32];
  __shared__ unsigned short sBh[64 * 32], sBl[64 * 32];
  int tid = threadIdx.x;
  int wave = tid >> 6, lane = tid & 63;
  int rowBase = blockIdx.x * 128;
  int colBase = blockIdx.y * 64;
  int rowHalf = (wave >> 1) * 64;
  int colHalf = (wave & 1) * 32;
  int l15 = lane & 15, quad = lane >> 4;

  f32x4 acc[4][2];
#pragma unroll
  for (int m = 0; m < 4; ++m)
#pragma unroll
    for (int n = 0; n < 2; ++n) acc[m][n] = (f32x4){0.f, 0.f, 0.f, 0.f};

  for (int kc = 0; kc < 4; ++kc) {
#pragma unroll
    for (int i = 0; i < 2; ++i) {
      int idx = tid + i * 256;  // 0..511
      int row = idx >> 2, seg = idx & 3;
      int gr = rowBase + row;
      if (FP32IN) {
        float4 v0 = make_float4(0.f, 0.f, 0.f, 0.f), v1 = v0;
        if (gr < nrows) {
          v0 = *(const float4*)&Af[(size_t)gr * 128 + kc * 32 + seg * 8];
          v1 = *(const float4*)&Af[(size_t)gr * 128 + kc * 32 + seg * 8 + 4];
        }
        ushort4 h0, l0, h1, l1;
        split4(v0, h0, l0);
        split4(v1, h1, l1);
        *(ushort4*)&sAh[row * 32 + seg * 8] = h0;
        *(ushort4*)&sAh[row * 32 + seg * 8 + 4] = h1;
        *(ushort4*)&sAl[row * 32 + seg * 8] = l0;
        *(ushort4*)&sAl[row * 32 + seg * 8 + 4] = l1;
      } else {
        uint4 vh = make_uint4(0, 0, 0, 0), vl = make_uint4(0, 0, 0, 0);
        if (gr < nrows) {
          vh = *(const uint4*)&Ah[(size_t)gr * 128 + kc * 32 + seg * 8];
          vl = *(const uint4*)&Al[(size_t)gr * 128 + kc * 32 + seg * 8];
        }
        *(uint4*)&sAh[row * 32 + seg * 8] = vh;
        *(uint4*)&sAl[row * 32 + seg * 8] = vl;
      }
    }
    {
      int col = tid >> 2, seg = tid & 3;
      *(uint4*)&sBh[col * 32 + seg * 8] =
          *(const uint4*)&BTh[(size_t)(colBase + col) * 128 + kc * 32 + seg * 8];
      *(uint4*)&sBl[col * 32 + seg * 8] =
          *(const uint4*)&BTl[(size_t)(colBase + col) * 128 + kc * 32 + seg * 8];
    }
    __syncthreads();

    bf16x8 afh[4], afl[4], bfh[2], bfl[2];
#pragma unroll
    for (int m = 0; m < 4; ++m) {
      int r = rowHalf + m * 16 + l15;
      afh[m] = *(const bf16x8*)&sAh[r * 32 + quad * 8];
      afl[m] = *(const bf16x8*)&sAl[r * 32 + quad * 8];
    }
#pragma unroll
    for (int n = 0; n < 2; ++n) {
      int cc = colHalf + n * 16 + l15;
      bfh[n] = *(const bf16x8*)&sBh[cc * 32 + quad * 8];
      bfl[n] = *(const bf16x8*)&sBl[cc * 32 + quad * 8];
    }
#pragma unroll
    for (int m = 0; m < 4; ++m)
#pragma unroll
      for (int n = 0; n < 2; ++n) {
        acc[m][n] = __builtin_amdgcn_mfma_f32_16x16x32_bf16(afh[m], bfh[n], acc[m][n], 0, 0, 0);
        acc[m][n] = __builtin_amdgcn_mfma_f32_16x16x32_bf16(afh[m], bfl[n], acc[m][n], 0, 0, 0);
        acc[m][n] = __builtin_amdgcn_mfma_f32_16x16x32_bf16(afl[m], bfh[n], acc[m][n], 0, 0, 0);
      }
    __syncthreads();
  }

  bool isL = (colBase < 128);
  float* __restrict__ C = isL ? Cl : Cr;
  int cb = (isL ? colBase : colBase - 128) + colHalf;
#pragma unroll
  for (int m = 0; m < 4; ++m)
#pragma unroll
    for (int r = 0; r < 4; ++r) {
      int grow = rowBase + rowHalf + m * 16 + quad * 4 + r;
      if (grow < nrows) {
#pragma unroll
        for (int n = 0; n < 2; ++n)
          C[(size_t)grow * 128 + cb + n * 16 + l15] = acc[m][n][r];
      }
    }
}

// ------------------------------ attention ----------------------------------
// One wave per node; 32 lanes/edge (float4/lane), halves process even/odd
// edges, 4 accumulators per half. Raw-exp softmax (no max), leaky folded
// into the dot via 0.6t+0.4|t| with att pre-scaled by log2e.
__global__ __launch_bounds__(256) void gat_attn(const float4* __restrict__ xl4,
                                                const float4* __restrict__ xr4,
                                                const int* __restrict__ row_start,
                                                const int* __restrict__ csr,
                                                const float* __restrict__ att,
                                                const float* __restrict__ bias,
                                                float* __restrict__ ofp,
                                                unsigned short* __restrict__ oh_hi,
                                                unsigned short* __restrict__ oh_lo,
                                                int n_nodes) {
  int node = blockIdx.x * 4 + (threadIdx.x >> 6);
  if (node >= n_nodes) return;
  int lane = threadIdx.x & 63;
  int half = lane >> 5;
  int l31 = lane & 31;
  unsigned nb = (unsigned)node * 32 + l31;

  float4 xrd = xr4[nb];
  float4 a4 = *(const float4*)&att[l31 * 4];
  const float C06 = 0.6f * LOG2E, C04 = 0.4f * LOG2E;
  float4 a06 = make_float4(a4.x * C06, a4.y * C06, a4.z * C06, a4.w * C06);
  float4 a04 = make_float4(a4.x * C04, a4.y * C04, a4.z * C04, a4.w * C04);

  float l[4];
  float4 acc[4];
#pragma unroll
  for (int j = 0; j < 4; ++j) {
    l[j] = 0.f;
    acc[j] = make_float4(0.f, 0.f, 0.f, 0.f);
  }

#define EDGE_E(xs, ee)                                                        \
  {                                                                           \
    float tx = (xs).x + xrd.x, ty = (xs).y + xrd.y;                           \
    float tz = (xs).z + xrd.z, tw = (xs).w + xrd.w;                           \
    ee = a06.x * tx;                                                          \
    ee = fmaf(a04.x, fabsf(tx), ee);                                          \
    ee = fmaf(a06.y, ty, ee);                                                 \
    ee = fmaf(a04.y, fabsf(ty), ee);                                          \
    ee = fmaf(a06.z, tz, ee);                                                 \
    ee = fmaf(a04.z, fabsf(tz), ee);                                          \
    ee = fmaf(a06.w, tw, ee);                                                 \
    ee = fmaf(a04.w, fabsf(tw), ee);                                          \
    ee += __shfl_xor(ee, 1);                                                  \
    ee += __shfl_xor(ee, 2);                                                  \
    ee += __shfl_xor(ee, 4);                                                  \
  }

  // self loop (counted once -> half 0's state 0)
  {
    float4 xs = xl4[nb];
    float e;
    EDGE_E(xs, e);
    float p = __builtin_amdgcn_exp2f(e);
    if (half == 0) {
      l[0] = p;
      acc[0] = make_float4(p * xs.x, p * xs.y, p * xs.z, p * xs.w);
    }
  }

  int beg = row_start[node], end = row_start[node + 1];
  int deg = end - beg;
  int fullEnd = beg + (deg & ~7);

  for (int base = beg; base < fullEnd; base += 8) {
    int b0 = base + half;
    int srcs[4];
    float4 xs[4];
    float e[4];
#pragma unroll
    for (int j = 0; j < 4; ++j) srcs[j] = csr[b0 + 2 * j];
#pragma unroll
    for (int j = 0; j < 4; ++j) xs[j] = xl4[(unsigned)srcs[j] * 32 + l31];
#pragma unroll
    for (int j = 0; j < 4; ++j) EDGE_E(xs[j], e[j]);
#pragma unroll
    for (int j = 0; j < 4; ++j) {
      float p = __builtin_amdgcn_exp2f(e[j]);
      l[j] += p;
      acc[j].x = fmaf(p, xs[j].x, acc[j].x);
      acc[j].y = fmaf(p, xs[j].y, acc[j].y);
      acc[j].z = fmaf(p, xs[j].z, acc[j].z);
      acc[j].w = fmaf(p, xs[j].w, acc[j].w);
    }
  }
  // tail: 2 edges/iter, masked
  for (int base = fullEnd; base < end; base += 2) {
    int idx = base + half;
    bool valid = idx < end;
    int src = csr[valid ? idx : (end - 1)];
    float4 xs = xl4[(unsigned)src * 32 + l31];
    float e;
    EDGE_E(xs, e);
    float p = valid ? __builtin_amdgcn_exp2f(e) : 0.f;
    l[0] += p;
    acc[0].x = fmaf(p, xs.x, acc[0].x);
    acc[0].y = fmaf(p, xs.y, acc[0].y);
    acc[0].z = fmaf(p, xs.z, acc[0].z);
    acc[0].w = fmaf(p, xs.w, acc[0].w);
  }
#undef EDGE_E

  // merge 4 states (plain adds -- common scale)
  float lt = (l[0] + l[1]) + (l[2] + l[3]);
  float4 at;
  at.x = (acc[0].x + acc[1].x) + (acc[2].x + acc[3].x);
  at.y = (acc[0].y + acc[1].y) + (acc[2].y + acc[3].y);
  at.z = (acc[0].z + acc[1].z) + (acc[2].z + acc[3].z);
  at.w = (acc[0].w + acc[1].w) + (acc[2].w + acc[3].w);
  // merge halves
  lt += __shfl_xor(lt, 32);
  at.x += __shfl_xor(at.x, 32);
  at.y += __shfl_xor(at.y, 32);
  at.z += __shfl_xor(at.z, 32);
  at.w += __shfl_xor(at.w, 32);

  if (half == 0) {
    float4 b4 = *(const float4*)&bias[l31 * 4];
    float inv = 1.f / (lt + 1e-16f);
    float4 o;
    o.x = fmaf(at.x, inv, b4.x);
    o.y = fmaf(at.y, inv, b4.y);
    o.z = fmaf(at.z, inv, b4.z);
    o.w = fmaf(at.w, inv, b4.w);
    // leaky 0.01: 0.505*o + 0.495*|o|
    o.x = fmaf(0.495f, fabsf(o.x), 0.505f * o.x);
    o.y = fmaf(0.495f, fabsf(o.y), 0.505f * o.y);
    o.z = fmaf(0.495f, fabsf(o.z), 0.505f * o.z);
    o.w = fmaf(0.495f, fabsf(o.w), 0.505f * o.w);
    if (ofp) *(float4*)&ofp[(size_t)nb * 4] = o;
    if (oh_hi) {
      ushort4 h, lo;
      split4(o, h, lo);
      *(ushort4*)&oh_hi[(size_t)nb * 4] = h;
      *(ushort4*)&oh_lo[(size_t)nb * 4] = lo;
    }
  }
}

// ------------------------------ classifier ---------------------------------
// One node per thread; Wc (128x16) + bc staged in LDS; float4 h reads.
__global__ __launch_bounds__(256) void classifier_kernel(const float4* __restrict__ h4,
                                                         const float* __restrict__ Wc,
                                                         const float* __restrict__ bc,
                                                         float* __restrict__ logits,
                                                         int n) {
  __shared__ float sW[2048];
  __shared__ float sb[16];
  int t = threadIdx.x;
#pragma unroll
  for (int i = 0; i < 8; ++i) sW[t + i * 256] = Wc[t + i * 256];
  if (t < 16) sb[t] = bc[t];
  __syncthreads();
  int node = blockIdx.x * 256 + t;
  if (node >= n) return;
  float acc[16];
#pragma unroll
  for (int o = 0; o < 16; ++o) acc[o] = sb[o];
  for (int c4 = 0; c4 < 32; ++c4) {
    float4 hv = h4[(unsigned)node * 32 + c4];
    const float* w = &sW[c4 * 64];
#pragma unroll
    for (int o = 0; o < 16; ++o) {
      acc[o] = fmaf(hv.x, w[o], acc[o]);
      acc[o] = fmaf(hv.y, w[16 + o], acc[o]);
      acc[o] = fmaf(hv.z, w[32 + o], acc[o]);
      acc[o] = fmaf(hv.w, w[48 + o], acc[o]);
    }
  }
#pragma unroll
  for (int q = 0; q < 4; ++q)
    *(float4*)&logits[(size_t)node * 16 + q * 4] =
        make_float4(acc[q * 4], acc[q * 4 + 1], acc[q * 4 + 2], acc[q * 4 + 3]);
}

// ---------------------------------------------------------------------------

extern "C" void kernel_launch(void* const* d_in, const int* in_sizes, int n_in,
                              void* d_out, int out_size, void* d_ws, size_t ws_size,
                              hipStream_t stream) {
  const float* x    = (const float*)d_in[0];
  const int*   ei   = (const int*)d_in[1];
  const float* Wl1  = (const float*)d_in[3];
  const float* Wr1  = (const float*)d_in[4];
  const float* att1 = (const float*)d_in[5];
  const float* b1   = (const float*)d_in[6];
  const float* Wl2  = (const float*)d_in[7];
  const float* Wr2  = (const float*)d_in[8];
  const float* att2 = (const float*)d_in[9];
  const float* b2   = (const float*)d_in[10];
  const float* Wc   = (const float*)d_in[11];
  const float* bc   = (const float*)d_in[12];

  const int N = in_sizes[0] / 128;
  const int E = in_sizes[1] / 2;

  float* outp   = (float*)d_out;
  float* logits = outp;                   // N*16 fp32
  float* hout   = outp + (size_t)N * 16;  // N*128 fp32 region
  // h1 bf16 hi/lo staged in the hout region (overwritten by fp32 h2 later)
  unsigned short* regionA = (unsigned short*)hout;
  unsigned short* regionB = regionA + (size_t)N * 128;

  char* ws = (char*)d_ws;
  float* xlbuf = (float*)ws;                  ws += (size_t)N * 128 * 4;
  float* xrbuf = (float*)ws;                  ws += (size_t)N * 128 * 4;
  unsigned short* WT1h = (unsigned short*)ws; ws += 256 * 128 * 2;
  unsigned short* WT1l = (unsigned short*)ws; ws += 256 * 128 * 2;
  unsigned short* WT2h = (unsigned short*)ws; ws += 256 * 128 * 2;
  unsigned short* WT2l = (unsigned short*)ws; ws += 256 * 128 * 2;
  int* cnt       = (int*)ws;                  ws += (size_t)N * 4;
  int* row_start = (int*)ws;                  ws += (size_t)(N + 1) * 4;
  int* wpos      = (int*)ws;                  ws += (size_t)N * 4;
  int* bsum      = (int*)ws;                  ws += 256 * 4;
  int* csr       = (int*)ws;                  ws += (size_t)E * 4;

  const int* esrc = ei;
  const int* edst = ei + E;

  int gN = (N + 255) / 256, gE = (E + 255) / 256;
  dim3 gGemm((N + 127) / 128, 4);
  int gAttn = (N + 3) / 4;

  // CSR build
  zero_i32<<<gN, 256, 0, stream>>>(cnt, N);
  count_kernel<<<gE, 256, 0, stream>>>(edst, cnt, E);
  scan_blk<<<gN, 256, 0, stream>>>(cnt, row_start, bsum, N);
  scan_bsum<<<1, 256, 0, stream>>>(bsum, gN, row_start, N);
  scan_add<<<gN, 256, 0, stream>>>(row_start, bsum, wpos, N);
  scatter_kernel<<<gE, 256, 0, stream>>>(esrc, edst, wpos, csr, E);

  // weight conversions
  convert_W<<<128, 256, 0, stream>>>(Wl1, Wr1, WT1h, WT1l);
  convert_W<<<128, 256, 0, stream>>>(Wl2, Wr2, WT2h, WT2l);

  // layer 1 (GEMM reads fp32 x, splits inline)
  gemm_mfma<true><<<gGemm, 256, 0, stream>>>(x, nullptr, nullptr, WT1h, WT1l,
                                             xlbuf, xrbuf, N);
  gat_attn<<<gAttn, 256, 0, stream>>>((const float4*)xlbuf, (const float4*)xrbuf,
                                      row_start, csr, att1, b1,
                                      nullptr, regionA, regionB, N);

  // layer 2 (reads h1 bf16 hi/lo)
  gemm_mfma<false><<<gGemm, 256, 0, stream>>>(nullptr, regionA, regionB, WT2h, WT2l,
                                              xlbuf, xrbuf, N);
  gat_attn<<<gAttn, 256, 0, stream>>>((const float4*)xlbuf, (const float4*)xrbuf,
                                      row_start, csr, att2, b2,
                                      hout, nullptr, nullptr, N);

  // classifier
  classifier_kernel<<<(N + 255) / 256, 256, 0, stream>>>((const float4*)hout, Wc, bc,
                                                         logits, N);
}

// Round 6
// 362.503 us; speedup vs baseline: 1.8489x; 1.0708x over previous
//
#include <hip/hip_runtime.h>
#include <hip/hip_fp16.h>

// ---------------------------------------------------------------------------
// GATv2 x2 + classifier. N=50000, E=800000, IN=128, HEADS=4, HID=32, OUT=16.
// R6: xl/xr stored fp16 (gather bytes halved; fp16 abs err ~2e-3 at |v|<=5,
//     8x safer than bf16). gat_attn: 16 lanes/edge (one b128 = 8ch/lane),
//     4 edge-slots/wave x 4-deep unroll = 16 edges in flight; head=4 lanes
//     -> 2-shfl score reduce; slot merge via shfl_xor(16/32) once per node.
//     csr padded by 16 so the masked tail iter loads unconditionally.
// ---------------------------------------------------------------------------

#define LOG2E 1.4426950408889634f

typedef short bf16x8 __attribute__((ext_vector_type(8)));
typedef float f32x4 __attribute__((ext_vector_type(4)));

__device__ __forceinline__ unsigned short f2bf(float f) {
  union { float f; unsigned u; } x; x.f = f;
  unsigned r = x.u + 0x7fffu + ((x.u >> 16) & 1u);
  return (unsigned short)(r >> 16);
}
__device__ __forceinline__ float bf2f(unsigned short h) {
  union { unsigned u; float f; } x; x.u = ((unsigned)h) << 16;
  return x.f;
}
__device__ __forceinline__ void split4(float4 v, ushort4& h, ushort4& l) {
  h.x = f2bf(v.x); l.x = f2bf(v.x - bf2f(h.x));
  h.y = f2bf(v.y); l.y = f2bf(v.y - bf2f(h.y));
  h.z = f2bf(v.z); l.z = f2bf(v.z - bf2f(h.z));
  h.w = f2bf(v.w); l.w = f2bf(v.w - bf2f(h.w));
}

// ------------------------------ CSR build ----------------------------------

__global__ __launch_bounds__(256) void zero_i32(int* __restrict__ p, int n) {
  int i = blockIdx.x * 256 + threadIdx.x;
  if (i < n) p[i] = 0;
}

__global__ __launch_bounds__(256) void count_kernel(const int* __restrict__ dst,
                                                    int* __restrict__ cnt, int E) {
  int i = blockIdx.x * 256 + threadIdx.x;
  if (i < E) atomicAdd(&cnt[dst[i]], 1);
}

__global__ __launch_bounds__(256) void scan_blk(const int* __restrict__ cnt,
                                                int* __restrict__ excl,
                                                int* __restrict__ bsum, int n) {
  __shared__ int s[256];
  int t = threadIdx.x, i = blockIdx.x * 256 + t;
  int v = (i < n) ? cnt[i] : 0;
  s[t] = v;
  __syncthreads();
#pragma unroll
  for (int off = 1; off < 256; off <<= 1) {
    int u = (t >= off) ? s[t - off] : 0;
    __syncthreads();
    s[t] += u;
    __syncthreads();
  }
  if (i < n) excl[i] = s[t] - v;
  if (t == 255) bsum[blockIdx.x] = s[255];
}

__global__ __launch_bounds__(256) void scan_bsum(int* __restrict__ bsum, int nb,
                                                 int* __restrict__ row_start, int n) {
  __shared__ int s[256];
  int t = threadIdx.x;
  int v = (t < nb) ? bsum[t] : 0;
  s[t] = v;
  __syncthreads();
#pragma unroll
  for (int off = 1; off < 256; off <<= 1) {
    int u = (t >= off) ? s[t - off] : 0;
    __syncthreads();
    s[t] += u;
    __syncthreads();
  }
  if (t < nb) bsum[t] = s[t] - v;
  if (t == 255) row_start[n] = s[255];
}

__global__ __launch_bounds__(256) void scan_add(int* __restrict__ row_start,
                                                const int* __restrict__ bsum,
                                                int* __restrict__ wpos, int n) {
  int i = blockIdx.x * 256 + threadIdx.x;
  if (i < n) {
    int r = row_start[i] + bsum[blockIdx.x];
    row_start[i] = r;
    wpos[i] = r;
  }
}

__global__ __launch_bounds__(256) void scatter_kernel(const int* __restrict__ src,
                                                      const int* __restrict__ dst,
                                                      int* __restrict__ wpos,
                                                      int* __restrict__ csr, int E) {
  int i = blockIdx.x * 256 + threadIdx.x;
  if (i < E) {
    int d = dst[i];
    int p = atomicAdd(&wpos[d], 1);
    csr[p] = src[i];
  }
}

// --------------------------- weight converts -------------------------------

__global__ __launch_bounds__(256) void convert_W(const float* __restrict__ Wl,
                                                 const float* __restrict__ Wr,
                                                 unsigned short* __restrict__ BTh,
                                                 unsigned short* __restrict__ BTl) {
  int idx = blockIdx.x * 256 + threadIdx.x;  // 0..32767
  int col = idx >> 7, k = idx & 127;
  float v = (col < 128) ? Wl[k * 128 + col] : Wr[k * 128 + (col - 128)];
  unsigned short h = f2bf(v);
  BTh[idx] = h;
  BTl[idx] = f2bf(v - bf2f(h));
}

// ------------------------------ MFMA GEMM ----------------------------------
// C[N x 256] = A[N x 128] @ W[128 x 256], split-bf16 3-term; C stored fp16.
template <bool FP32IN>
__global__ __launch_bounds__(256) void gemm_mfma(
    const float* __restrict__ Af,
    const unsigned short* __restrict__ Ah, const unsigned short* __restrict__ Al,
    const unsigned short* __restrict__ BTh, const unsigned short* __restrict__ BTl,
    __half* __restrict__ Cl, __half* __restrict__ Cr, int nrows) {
  __shared__ unsigned short sAh[128 * 32], sAl[128 * 32];
  __shared__ unsigned short sBh[64 * 32], sBl[64 * 32];
  int tid = threadIdx.x;
  int wave = tid >> 6, lane = tid & 63;
  int rowBase = blockIdx.x * 128;
  int colBase = blockIdx.y * 64;
  int rowHalf = (wave >> 1) * 64;
  int colHalf = (wave & 1) * 32;
  int l15 = lane & 15, quad = lane >> 4;

  f32x4 acc[4][2];
#pragma unroll
  for (int m = 0; m < 4; ++m)
#pragma unroll
    for (int n = 0; n < 2; ++n) acc[m][n] = (f32x4){0.f, 0.f, 0.f, 0.f};

  for (int kc = 0; kc < 4; ++kc) {
#pragma unroll
    for (int i = 0; i < 2; ++i) {
      int idx = tid + i * 256;  // 0..511
      int row = idx >> 2, seg = idx & 3;
      int gr = rowBase + row;
      if (FP32IN) {
        float4 v0 = make_float4(0.f, 0.f, 0.f, 0.f), v1 = v0;
        if (gr < nrows) {
          v0 = *(const float4*)&Af[(size_t)gr * 128 + kc * 32 + seg * 8];
          v1 = *(const float4*)&Af[(size_t)gr * 128 + kc * 32 + seg * 8 + 4];
        }
        ushort4 h0, l0, h1, l1;
        split4(v0, h0, l0);
        split4(v1, h1, l1);
        *(ushort4*)&sAh[row * 32 + seg * 8] = h0;
        *(ushort4*)&sAh[row * 32 + seg * 8 + 4] = h1;
        *(ushort4*)&sAl[row * 32 + seg * 8] = l0;
        *(ushort4*)&sAl[row * 32 + seg * 8 + 4] = l1;
      } else {
        uint4 vh = make_uint4(0, 0, 0, 0), vl = make_uint4(0, 0, 0, 0);
        if (gr < nrows) {
          vh = *(const uint4*)&Ah[(size_t)gr * 128 + kc * 32 + seg * 8];
          vl = *(const uint4*)&Al[(size_t)gr * 128 + kc * 32 + seg * 8];
        }
        *(uint4*)&sAh[row * 32 + seg * 8] = vh;
        *(uint4*)&sAl[row * 32 + seg * 8] = vl;
      }
    }
    {
      int col = tid >> 2, seg = tid & 3;
      *(uint4*)&sBh[col * 32 + seg * 8] =
          *(const uint4*)&BTh[(size_t)(colBase + col) * 128 + kc * 32 + seg * 8];
      *(uint4*)&sBl[col * 32 + seg * 8] =
          *(const uint4*)&BTl[(size_t)(colBase + col) * 128 + kc * 32 + seg * 8];
    }
    __syncthreads();

    bf16x8 afh[4], afl[4], bfh[2], bfl[2];
#pragma unroll
    for (int m = 0; m < 4; ++m) {
      int r = rowHalf + m * 16 + l15;
      afh[m] = *(const bf16x8*)&sAh[r * 32 + quad * 8];
      afl[m] = *(const bf16x8*)&sAl[r * 32 + quad * 8];
    }
#pragma unroll
    for (int n = 0; n < 2; ++n) {
      int cc = colHalf + n * 16 + l15;
      bfh[n] = *(const bf16x8*)&sBh[cc * 32 + quad * 8];
      bfl[n] = *(const bf16x8*)&sBl[cc * 32 + quad * 8];
    }
#pragma unroll
    for (int m = 0; m < 4; ++m)
#pragma unroll
      for (int n = 0; n < 2; ++n) {
        acc[m][n] = __builtin_amdgcn_mfma_f32_16x16x32_bf16(afh[m], bfh[n], acc[m][n], 0, 0, 0);
        acc[m][n] = __builtin_amdgcn_mfma_f32_16x16x32_bf16(afh[m], bfl[n], acc[m][n], 0, 0, 0);
        acc[m][n] = __builtin_amdgcn_mfma_f32_16x16x32_bf16(afl[m], bfh[n], acc[m][n], 0, 0, 0);
      }
    __syncthreads();
  }

  bool isL = (colBase < 128);
  __half* __restrict__ C = isL ? Cl : Cr;
  int cb = (isL ? colBase : colBase - 128) + colHalf;
#pragma unroll
  for (int m = 0; m < 4; ++m)
#pragma unroll
    for (int r = 0; r < 4; ++r) {
      int grow = rowBase + rowHalf + m * 16 + quad * 4 + r;
      if (grow < nrows) {
#pragma unroll
        for (int n = 0; n < 2; ++n)
          C[(size_t)grow * 128 + cb + n * 16 + l15] = __float2half(acc[m][n][r]);
      }
    }
}

// ------------------------------ attention ----------------------------------
// One wave per node. 16 lanes/edge (8 ch/lane, one b128 fp16 load);
// 4 edge-slots per wave, each slot unrolled x4 -> 16 edges in flight.
// Head = 32ch = 4 lanes -> 2-shfl score reduce. Slots merged at end.
__global__ __launch_bounds__(256) void gat_attn(const __half* __restrict__ xl,
                                                const __half* __restrict__ xr,
                                                const int* __restrict__ row_start,
                                                const int* __restrict__ csr,
                                                const float* __restrict__ att,
                                                const float* __restrict__ bias,
                                                float* __restrict__ ofp,
                                                unsigned short* __restrict__ oh_hi,
                                                unsigned short* __restrict__ oh_lo,
                                                int n_nodes) {
  int node = blockIdx.x * 4 + (threadIdx.x >> 6);
  if (node >= n_nodes) return;
  int lane = threadIdx.x & 63;
  int slot = lane >> 4;
  int l15 = lane & 15;
  int c0 = l15 * 8;

  // xr row (fp16 -> fp32)
  float fxr[8];
  {
    uint4 raw = *(const uint4*)&xr[(size_t)node * 128 + c0];
    const __half2* hp = (const __half2*)&raw;
#pragma unroll
    for (int k = 0; k < 4; ++k) {
      float2 f = __half22float2(hp[k]);
      fxr[2 * k] = f.x; fxr[2 * k + 1] = f.y;
    }
  }
  // att row, pre-scaled: a06 = 0.6*log2e*a, a04 = 0.4*log2e*a
  float a06[8], a04[8];
  {
    float4 a0 = *(const float4*)&att[c0];
    float4 a1 = *(const float4*)&att[c0 + 4];
    float av[8] = {a0.x, a0.y, a0.z, a0.w, a1.x, a1.y, a1.z, a1.w};
    const float C06 = 0.6f * LOG2E, C04 = 0.4f * LOG2E;
#pragma unroll
    for (int k = 0; k < 8; ++k) { a06[k] = av[k] * C06; a04[k] = av[k] * C04; }
  }

  float acc[8];
#pragma unroll
  for (int k = 0; k < 8; ++k) acc[k] = 0.f;
  float lsum = 0.f;

#define EDGE_BODY(SRC, PVALID)                                                 \
  {                                                                            \
    uint4 raw = *(const uint4*)&xl[(size_t)(unsigned)(SRC)*128 + c0];          \
    const __half2* hp = (const __half2*)&raw;                                  \
    float fs[8];                                                               \
    _Pragma("unroll") for (int k = 0; k < 4; ++k) {                            \
      float2 f = __half22float2(hp[k]);                                        \
      fs[2 * k] = f.x; fs[2 * k + 1] = f.y;                                    \
    }                                                                          \
    float e = 0.f;                                                             \
    _Pragma("unroll") for (int k = 0; k < 8; ++k) {                            \
      float t = fs[k] + fxr[k];                                                \
      e = fmaf(a06[k], t, e);                                                  \
      e = fmaf(a04[k], fabsf(t), e);                                           \
    }                                                                          \
    e += __shfl_xor(e, 1);                                                     \
    e += __shfl_xor(e, 2);                                                     \
    float p = (PVALID) ? __builtin_amdgcn_exp2f(e) : 0.f;                      \
    lsum += p;                                                                 \
    _Pragma("unroll") for (int k = 0; k < 8; ++k)                              \
        acc[k] = fmaf(p, fs[k], acc[k]);                                       \
  }

  // self loop: only slot 0 accumulates
  EDGE_BODY(node, slot == 0);

  int beg = row_start[node], end = row_start[node + 1];
  int deg = end - beg;
  int fullEnd = beg + (deg & ~15);
  int b0 = beg + 4 * slot;

  for (int base = beg; base < fullEnd; base += 16, b0 += 16) {
    int s0 = csr[b0], s1 = csr[b0 + 1], s2 = csr[b0 + 2], s3 = csr[b0 + 3];
    EDGE_BODY(s0, true);
    EDGE_BODY(s1, true);
    EDGE_BODY(s2, true);
    EDGE_BODY(s3, true);
  }
  if (fullEnd < end) {  // one masked iter (csr padded by 16)
    int s0 = csr[b0], s1 = csr[b0 + 1], s2 = csr[b0 + 2], s3 = csr[b0 + 3];
    EDGE_BODY(s0, b0 + 0 < end);
    EDGE_BODY(s1, b0 + 1 < end);
    EDGE_BODY(s2, b0 + 2 < end);
    EDGE_BODY(s3, b0 + 3 < end);
  }
#undef EDGE_BODY

  // merge the 4 slots (same channels live in lanes with equal l15)
  lsum += __shfl_xor(lsum, 16);
  lsum += __shfl_xor(lsum, 32);
#pragma unroll
  for (int k = 0; k < 8; ++k) {
    acc[k] += __shfl_xor(acc[k], 16);
    acc[k] += __shfl_xor(acc[k], 32);
  }

  if (slot == 0) {
    float4 b0v = *(const float4*)&bias[c0];
    float4 b1v = *(const float4*)&bias[c0 + 4];
    float bv[8] = {b0v.x, b0v.y, b0v.z, b0v.w, b1v.x, b1v.y, b1v.z, b1v.w};
    float inv = 1.f / (lsum + 1e-16f);
    float o[8];
#pragma unroll
    for (int k = 0; k < 8; ++k) {
      float v = fmaf(acc[k], inv, bv[k]);
      o[k] = fmaf(0.495f, fabsf(v), 0.505f * v);  // leaky 0.01
    }
    if (ofp) {
      *(float4*)&ofp[(size_t)node * 128 + c0] = make_float4(o[0], o[1], o[2], o[3]);
      *(float4*)&ofp[(size_t)node * 128 + c0 + 4] = make_float4(o[4], o[5], o[6], o[7]);
    }
    if (oh_hi) {
      ushort4 h0, l0, h1, l1;
      split4(make_float4(o[0], o[1], o[2], o[3]), h0, l0);
      split4(make_float4(o[4], o[5], o[6], o[7]), h1, l1);
      *(ushort4*)&oh_hi[(size_t)node * 128 + c0] = h0;
      *(ushort4*)&oh_hi[(size_t)node * 128 + c0 + 4] = h1;
      *(ushort4*)&oh_lo[(size_t)node * 128 + c0] = l0;
      *(ushort4*)&oh_lo[(size_t)node * 128 + c0 + 4] = l1;
    }
  }
}

// ------------------------------ classifier ---------------------------------
__global__ __launch_bounds__(256) void classifier_kernel(const float4* __restrict__ h4,
                                                         const float* __restrict__ Wc,
                                                         const float* __restrict__ bc,
                                                         float* __restrict__ logits,
                                                         int n) {
  __shared__ float sW[2048];
  __shared__ float sb[16];
  int t = threadIdx.x;
#pragma unroll
  for (int i = 0; i < 8; ++i) sW[t + i * 256] = Wc[t + i * 256];
  if (t < 16) sb[t] = bc[t];
  __syncthreads();
  int node = blockIdx.x * 256 + t;
  if (node >= n) return;
  float acc[16];
#pragma unroll
  for (int o = 0; o < 16; ++o) acc[o] = sb[o];
  for (int c4 = 0; c4 < 32; ++c4) {
    float4 hv = h4[(unsigned)node * 32 + c4];
    const float* w = &sW[c4 * 64];
#pragma unroll
    for (int o = 0; o < 16; ++o) {
      acc[o] = fmaf(hv.x, w[o], acc[o]);
      acc[o] = fmaf(hv.y, w[16 + o], acc[o]);
      acc[o] = fmaf(hv.z, w[32 + o], acc[o]);
      acc[o] = fmaf(hv.w, w[48 + o], acc[o]);
    }
  }
#pragma unroll
  for (int q = 0; q < 4; ++q)
    *(float4*)&logits[(size_t)node * 16 + q * 4] =
        make_float4(acc[q * 4], acc[q * 4 + 1], acc[q * 4 + 2], acc[q * 4 + 3]);
}

// ---------------------------------------------------------------------------

extern "C" void kernel_launch(void* const* d_in, const int* in_sizes, int n_in,
                              void* d_out, int out_size, void* d_ws, size_t ws_size,
                              hipStream_t stream) {
  const float* x    = (const float*)d_in[0];
  const int*   ei   = (const int*)d_in[1];
  const float* Wl1  = (const float*)d_in[3];
  const float* Wr1  = (const float*)d_in[4];
  const float* att1 = (const float*)d_in[5];
  const float* b1   = (const float*)d_in[6];
  const float* Wl2  = (const float*)d_in[7];
  const float* Wr2  = (const float*)d_in[8];
  const float* att2 = (const float*)d_in[9];
  const float* b2   = (const float*)d_in[10];
  const float* Wc   = (const float*)d_in[11];
  const float* bc   = (const float*)d_in[12];

  const int N = in_sizes[0] / 128;
  const int E = in_sizes[1] / 2;

  float* outp   = (float*)d_out;
  float* logits = outp;                   // N*16 fp32
  float* hout   = outp + (size_t)N * 16;  // N*128 fp32 region
  // h1 bf16 hi/lo staged in the hout region (overwritten by fp32 h2 later)
  unsigned short* regionA = (unsigned short*)hout;
  unsigned short* regionB = regionA + (size_t)N * 128;

  char* ws = (char*)d_ws;
  __half* xlbuf = (__half*)ws;                ws += (size_t)N * 128 * 2;
  __half* xrbuf = (__half*)ws;                ws += (size_t)N * 128 * 2;
  unsigned short* WT1h = (unsigned short*)ws; ws += 256 * 128 * 2;
  unsigned short* WT1l = (unsigned short*)ws; ws += 256 * 128 * 2;
  unsigned short* WT2h = (unsigned short*)ws; ws += 256 * 128 * 2;
  unsigned short* WT2l = (unsigned short*)ws; ws += 256 * 128 * 2;
  int* cnt       = (int*)ws;                  ws += (size_t)N * 4;
  int* row_start = (int*)ws;                  ws += (size_t)(N + 1) * 4;
  int* wpos      = (int*)ws;                  ws += (size_t)N * 4;
  int* bsum      = (int*)ws;                  ws += 256 * 4;
  int* csr       = (int*)ws;                  ws += (size_t)(E + 16) * 4;

  const int* esrc = ei;
  const int* edst = ei + E;

  int gN = (N + 255) / 256, gE = (E + 255) / 256;
  dim3 gGemm((N + 127) / 128, 4);
  int gAttn = (N + 3) / 4;

  // CSR build
  zero_i32<<<gN, 256, 0, stream>>>(cnt, N);
  count_kernel<<<gE, 256, 0, stream>>>(edst, cnt, E);
  scan_blk<<<gN, 256, 0, stream>>>(cnt, row_start, bsum, N);
  scan_bsum<<<1, 256, 0, stream>>>(bsum, gN, row_start, N);
  scan_add<<<gN, 256, 0, stream>>>(row_start, bsum, wpos, N);
  scatter_kernel<<<gE, 256, 0, stream>>>(esrc, edst, wpos, csr, E);
  zero_i32<<<1, 256, 0, stream>>>(csr + E, 16);  // pad for masked tail iter

  // weight conversions
  convert_W<<<128, 256, 0, stream>>>(Wl1, Wr1, WT1h, WT1l);
  convert_W<<<128, 256, 0, stream>>>(Wl2, Wr2, WT2h, WT2l);

  // layer 1 (GEMM reads fp32 x, splits inline; writes fp16 xl/xr)
  gemm_mfma<true><<<gGemm, 256, 0, stream>>>(x, nullptr, nullptr, WT1h, WT1l,
                                             xlbuf, xrbuf, N);
  gat_attn<<<gAttn, 256, 0, stream>>>(xlbuf, xrbuf, row_start, csr, att1, b1,
                                      nullptr, regionA, regionB, N);

  // layer 2 (reads h1 bf16 hi/lo; writes fp16 xl/xr)
  gemm_mfma<false><<<gGemm, 256, 0, stream>>>(nullptr, regionA, regionB, WT2h, WT2l,
                                              xlbuf, xrbuf, N);
  gat_attn<<<gAttn, 256, 0, stream>>>(xlbuf, xrbuf, row_start, csr, att2, b2,
                                      hout, nullptr, nullptr, N);

  // classifier
  classifier_kernel<<<(N + 255) / 256, 256, 0, stream>>>((const float4*)hout, Wc, bc,
                                                         logits, N);
}

// Round 7
// 346.886 us; speedup vs baseline: 1.9321x; 1.0450x over previous
//
#include <hip/hip_runtime.h>
#include <hip/hip_fp16.h>

// ---------------------------------------------------------------------------
// GATv2 x2 + classifier. N=50000, E=800000, IN=128, HEADS=4, HID=32, OUT=16.
// R7: attn padding diet: self-loop folded into CSR (counts+1, csr[beg]=node),
//     tail granularity 4 edges (was a fixed 16-slot tail -> ~47% of edge
//     bodies were padding at mean degree 16). fma-mix friendly aggregation
//     (half fed straight to fmaf). convert_W single dispatch.
// ---------------------------------------------------------------------------

#define LOG2E 1.4426950408889634f

typedef short bf16x8 __attribute__((ext_vector_type(8)));
typedef float f32x4 __attribute__((ext_vector_type(4)));

__device__ __forceinline__ unsigned short f2bf(float f) {
  union { float f; unsigned u; } x; x.f = f;
  unsigned r = x.u + 0x7fffu + ((x.u >> 16) & 1u);
  return (unsigned short)(r >> 16);
}
__device__ __forceinline__ float bf2f(unsigned short h) {
  union { unsigned u; float f; } x; x.u = ((unsigned)h) << 16;
  return x.f;
}
__device__ __forceinline__ void split4(float4 v, ushort4& h, ushort4& l) {
  h.x = f2bf(v.x); l.x = f2bf(v.x - bf2f(h.x));
  h.y = f2bf(v.y); l.y = f2bf(v.y - bf2f(h.y));
  h.z = f2bf(v.z); l.z = f2bf(v.z - bf2f(h.z));
  h.w = f2bf(v.w); l.w = f2bf(v.w - bf2f(h.w));
}

// ------------------------------ CSR build ----------------------------------

__global__ __launch_bounds__(256) void zero_i32(int* __restrict__ p, int n) {
  int i = blockIdx.x * 256 + threadIdx.x;
  if (i < n) p[i] = 0;
}

__global__ __launch_bounds__(256) void count_kernel(const int* __restrict__ dst,
                                                    int* __restrict__ cnt, int E) {
  int i = blockIdx.x * 256 + threadIdx.x;
  if (i < E) atomicAdd(&cnt[dst[i]], 1);
}

// per-block scan of (cnt[i]+1)  (+1 = self loop slot)
__global__ __launch_bounds__(256) void scan_blk(const int* __restrict__ cnt,
                                                int* __restrict__ excl,
                                                int* __restrict__ bsum, int n) {
  __shared__ int s[256];
  int t = threadIdx.x, i = blockIdx.x * 256 + t;
  int v = (i < n) ? (cnt[i] + 1) : 0;
  s[t] = v;
  __syncthreads();
#pragma unroll
  for (int off = 1; off < 256; off <<= 1) {
    int u = (t >= off) ? s[t - off] : 0;
    __syncthreads();
    s[t] += u;
    __syncthreads();
  }
  if (i < n) excl[i] = s[t] - v;
  if (t == 255) bsum[blockIdx.x] = s[255];
}

__global__ __launch_bounds__(256) void scan_bsum(int* __restrict__ bsum, int nb,
                                                 int* __restrict__ row_start, int n) {
  __shared__ int s[256];
  int t = threadIdx.x;
  int v = (t < nb) ? bsum[t] : 0;
  s[t] = v;
  __syncthreads();
#pragma unroll
  for (int off = 1; off < 256; off <<= 1) {
    int u = (t >= off) ? s[t - off] : 0;
    __syncthreads();
    s[t] += u;
    __syncthreads();
  }
  if (t < nb) bsum[t] = s[t] - v;
  if (t == 255) row_start[n] = s[255];
}

// add block offsets; write self-loop entry; wpos starts past it
__global__ __launch_bounds__(256) void scan_add(int* __restrict__ row_start,
                                                const int* __restrict__ bsum,
                                                int* __restrict__ wpos,
                                                int* __restrict__ csr, int n) {
  int i = blockIdx.x * 256 + threadIdx.x;
  if (i < n) {
    int r = row_start[i] + bsum[blockIdx.x];
    row_start[i] = r;
    wpos[i] = r + 1;
    csr[r] = i;  // self loop first in each row
  }
}

__global__ __launch_bounds__(256) void scatter_kernel(const int* __restrict__ src,
                                                      const int* __restrict__ dst,
                                                      int* __restrict__ wpos,
                                                      int* __restrict__ csr, int E) {
  int i = blockIdx.x * 256 + threadIdx.x;
  if (i < E) {
    int d = dst[i];
    int p = atomicAdd(&wpos[d], 1);
    csr[p] = src[i];
  }
}

// --------------------------- weight converts -------------------------------
// both layers in one dispatch: 256 blocks, blocks 0-127 layer1, 128-255 layer2
__global__ __launch_bounds__(256) void convert_W(const float* __restrict__ Wl1,
                                                 const float* __restrict__ Wr1,
                                                 const float* __restrict__ Wl2,
                                                 const float* __restrict__ Wr2,
                                                 unsigned short* __restrict__ BT1h,
                                                 unsigned short* __restrict__ BT1l,
                                                 unsigned short* __restrict__ BT2h,
                                                 unsigned short* __restrict__ BT2l) {
  int b = blockIdx.x;
  const float* Wl = (b < 128) ? Wl1 : Wl2;
  const float* Wr = (b < 128) ? Wr1 : Wr2;
  unsigned short* BTh = (b < 128) ? BT1h : BT2h;
  unsigned short* BTl = (b < 128) ? BT1l : BT2l;
  int idx = (b & 127) * 256 + threadIdx.x;  // 0..32767
  int col = idx >> 7, k = idx & 127;
  float v = (col < 128) ? Wl[k * 128 + col] : Wr[k * 128 + (col - 128)];
  unsigned short h = f2bf(v);
  BTh[idx] = h;
  BTl[idx] = f2bf(v - bf2f(h));
}

// ------------------------------ MFMA GEMM ----------------------------------
// C[N x 256] = A[N x 128] @ W[128 x 256], split-bf16 3-term; C stored fp16.
template <bool FP32IN>
__global__ __launch_bounds__(256) void gemm_mfma(
    const float* __restrict__ Af,
    const unsigned short* __restrict__ Ah, const unsigned short* __restrict__ Al,
    const unsigned short* __restrict__ BTh, const unsigned short* __restrict__ BTl,
    __half* __restrict__ Cl, __half* __restrict__ Cr, int nrows) {
  __shared__ unsigned short sAh[128 * 32], sAl[128 * 32];
  __shared__ unsigned short sBh[64 * 32], sBl[64 * 32];
  int tid = threadIdx.x;
  int wave = tid >> 6, lane = tid & 63;
  int rowBase = blockIdx.x * 128;
  int colBase = blockIdx.y * 64;
  int rowHalf = (wave >> 1) * 64;
  int colHalf = (wave & 1) * 32;
  int l15 = lane & 15, quad = lane >> 4;

  f32x4 acc[4][2];
#pragma unroll
  for (int m = 0; m < 4; ++m)
#pragma unroll
    for (int n = 0; n < 2; ++n) acc[m][n] = (f32x4){0.f, 0.f, 0.f, 0.f};

  for (int kc = 0; kc < 4; ++kc) {
#pragma unroll
    for (int i = 0; i < 2; ++i) {
      int idx = tid + i * 256;  // 0..511
      int row = idx >> 2, seg = idx & 3;
      int gr = rowBase + row;
      if (FP32IN) {
        float4 v0 = make_float4(0.f, 0.f, 0.f, 0.f), v1 = v0;
        if (gr < nrows) {
          v0 = *(const float4*)&Af[(size_t)gr * 128 + kc * 32 + seg * 8];
          v1 = *(const float4*)&Af[(size_t)gr * 128 + kc * 32 + seg * 8 + 4];
        }
        ushort4 h0, l0, h1, l1;
        split4(v0, h0, l0);
        split4(v1, h1, l1);
        *(ushort4*)&sAh[row * 32 + seg * 8] = h0;
        *(ushort4*)&sAh[row * 32 + seg * 8 + 4] = h1;
        *(ushort4*)&sAl[row * 32 + seg * 8] = l0;
        *(ushort4*)&sAl[row * 32 + seg * 8 + 4] = l1;
      } else {
        uint4 vh = make_uint4(0, 0, 0, 0), vl = make_uint4(0, 0, 0, 0);
        if (gr < nrows) {
          vh = *(const uint4*)&Ah[(size_t)gr * 128 + kc * 32 + seg * 8];
          vl = *(const uint4*)&Al[(size_t)gr * 128 + kc * 32 + seg * 8];
        }
        *(uint4*)&sAh[row * 32 + seg * 8] = vh;
        *(uint4*)&sAl[row * 32 + seg * 8] = vl;
      }
    }
    {
      int col = tid >> 2, seg = tid & 3;
      *(uint4*)&sBh[col * 32 + seg * 8] =
          *(const uint4*)&BTh[(size_t)(colBase + col) * 128 + kc * 32 + seg * 8];
      *(uint4*)&sBl[col * 32 + seg * 8] =
          *(const uint4*)&BTl[(size_t)(colBase + col) * 128 + kc * 32 + seg * 8];
    }
    __syncthreads();

    bf16x8 afh[4], afl[4], bfh[2], bfl[2];
#pragma unroll
    for (int m = 0; m < 4; ++m) {
      int r = rowHalf + m * 16 + l15;
      afh[m] = *(const bf16x8*)&sAh[r * 32 + quad * 8];
      afl[m] = *(const bf16x8*)&sAl[r * 32 + quad * 8];
    }
#pragma unroll
    for (int n = 0; n < 2; ++n) {
      int cc = colHalf + n * 16 + l15;
      bfh[n] = *(const bf16x8*)&sBh[cc * 32 + quad * 8];
      bfl[n] = *(const bf16x8*)&sBl[cc * 32 + quad * 8];
    }
#pragma unroll
    for (int m = 0; m < 4; ++m)
#pragma unroll
      for (int n = 0; n < 2; ++n) {
        acc[m][n] = __builtin_amdgcn_mfma_f32_16x16x32_bf16(afh[m], bfh[n], acc[m][n], 0, 0, 0);
        acc[m][n] = __builtin_amdgcn_mfma_f32_16x16x32_bf16(afh[m], bfl[n], acc[m][n], 0, 0, 0);
        acc[m][n] = __builtin_amdgcn_mfma_f32_16x16x32_bf16(afl[m], bfh[n], acc[m][n], 0, 0, 0);
      }
    __syncthreads();
  }

  bool isL = (colBase < 128);
  __half* __restrict__ C = isL ? Cl : Cr;
  int cb = (isL ? colBase : colBase - 128) + colHalf;
#pragma unroll
  for (int m = 0; m < 4; ++m)
#pragma unroll
    for (int r = 0; r < 4; ++r) {
      int grow = rowBase + rowHalf + m * 16 + quad * 4 + r;
      if (grow < nrows) {
#pragma unroll
        for (int n = 0; n < 2; ++n)
          C[(size_t)grow * 128 + cb + n * 16 + l15] = __float2half(acc[m][n][r]);
      }
    }
}

// ------------------------------ attention ----------------------------------
// One wave per node; 16 lanes/edge (8 ch/lane, one b128 fp16 load);
// 4 edge-slots/wave. Main loop 16 edges/iter, tail 4 edges/iter.
// Self loop lives in csr (csr[beg] = node).
__global__ __launch_bounds__(256) void gat_attn(const __half* __restrict__ xl,
                                                const __half* __restrict__ xr,
                                                const int* __restrict__ row_start,
                                                const int* __restrict__ csr,
                                                const float* __restrict__ att,
                                                const float* __restrict__ bias,
                                                float* __restrict__ ofp,
                                                unsigned short* __restrict__ oh_hi,
                                                unsigned short* __restrict__ oh_lo,
                                                int n_nodes) {
  int node = blockIdx.x * 4 + (threadIdx.x >> 6);
  if (node >= n_nodes) return;
  int lane = threadIdx.x & 63;
  int slot = lane >> 4;
  int l15 = lane & 15;
  int c0 = l15 * 8;

  // xr row (fp16 -> fp32)
  float fxr[8];
  {
    uint4 raw = *(const uint4*)&xr[(size_t)node * 128 + c0];
    const __half* hp = (const __half*)&raw;
#pragma unroll
    for (int k = 0; k < 8; ++k) fxr[k] = __half2float(hp[k]);
  }
  // att row, pre-scaled: a06 = 0.6*log2e*a, a04 = 0.4*log2e*a
  float a06[8], a04[8];
  {
    float4 a0 = *(const float4*)&att[c0];
    float4 a1 = *(const float4*)&att[c0 + 4];
    float av[8] = {a0.x, a0.y, a0.z, a0.w, a1.x, a1.y, a1.z, a1.w};
    const float C06 = 0.6f * LOG2E, C04 = 0.4f * LOG2E;
#pragma unroll
    for (int k = 0; k < 8; ++k) { a06[k] = av[k] * C06; a04[k] = av[k] * C04; }
  }

  float acc[8];
#pragma unroll
  for (int k = 0; k < 8; ++k) acc[k] = 0.f;
  float lsum = 0.f;

#define EDGE_BODY(SRC, PVALID)                                                 \
  {                                                                            \
    uint4 raw = *(const uint4*)&xl[(size_t)(unsigned)(SRC)*128 + c0];          \
    const __half* hp = (const __half*)&raw;                                    \
    float e = 0.f;                                                             \
    _Pragma("unroll") for (int k = 0; k < 8; ++k) {                            \
      float t = __half2float(hp[k]) + fxr[k];                                  \
      e = fmaf(a06[k], t, e);                                                  \
      e = fmaf(a04[k], fabsf(t), e);                                           \
    }                                                                          \
    e += __shfl_xor(e, 1);                                                     \
    e += __shfl_xor(e, 2);                                                     \
    float p = (PVALID) ? __builtin_amdgcn_exp2f(e) : 0.f;                      \
    lsum += p;                                                                 \
    _Pragma("unroll") for (int k = 0; k < 8; ++k)                              \
        acc[k] = fmaf(p, __half2float(hp[k]), acc[k]);                         \
  }

  int beg = row_start[node], end = row_start[node + 1];
  int deg = end - beg;  // includes self
  int fullEnd = beg + (deg & ~15);

  for (int base = beg; base < fullEnd; base += 16) {
    int b0 = base + 4 * slot;
    int s0 = csr[b0], s1 = csr[b0 + 1], s2 = csr[b0 + 2], s3 = csr[b0 + 3];
    EDGE_BODY(s0, true);
    EDGE_BODY(s1, true);
    EDGE_BODY(s2, true);
    EDGE_BODY(s3, true);
  }
  for (int base = fullEnd; base < end; base += 4) {  // csr padded by 16
    int idx = base + slot;
    int src = csr[idx];
    EDGE_BODY(src, idx < end);
  }
#undef EDGE_BODY

  // merge the 4 slots (same channels live in lanes with equal l15)
  lsum += __shfl_xor(lsum, 16);
  lsum += __shfl_xor(lsum, 32);
#pragma unroll
  for (int k = 0; k < 8; ++k) {
    acc[k] += __shfl_xor(acc[k], 16);
    acc[k] += __shfl_xor(acc[k], 32);
  }

  if (slot == 0) {
    float4 b0v = *(const float4*)&bias[c0];
    float4 b1v = *(const float4*)&bias[c0 + 4];
    float bv[8] = {b0v.x, b0v.y, b0v.z, b0v.w, b1v.x, b1v.y, b1v.z, b1v.w};
    float inv = 1.f / (lsum + 1e-16f);
    float o[8];
#pragma unroll
    for (int k = 0; k < 8; ++k) {
      float v = fmaf(acc[k], inv, bv[k]);
      o[k] = fmaf(0.495f, fabsf(v), 0.505f * v);  // leaky 0.01
    }
    if (ofp) {
      *(float4*)&ofp[(size_t)node * 128 + c0] = make_float4(o[0], o[1], o[2], o[3]);
      *(float4*)&ofp[(size_t)node * 128 + c0 + 4] = make_float4(o[4], o[5], o[6], o[7]);
    }
    if (oh_hi) {
      ushort4 h0, l0, h1, l1;
      split4(make_float4(o[0], o[1], o[2], o[3]), h0, l0);
      split4(make_float4(o[4], o[5], o[6], o[7]), h1, l1);
      *(ushort4*)&oh_hi[(size_t)node * 128 + c0] = h0;
      *(ushort4*)&oh_hi[(size_t)node * 128 + c0 + 4] = h1;
      *(ushort4*)&oh_lo[(size_t)node * 128 + c0] = l0;
      *(ushort4*)&oh_lo[(size_t)node * 128 + c0 + 4] = l1;
    }
  }
}

// ------------------------------ classifier ---------------------------------
__global__ __launch_bounds__(256) void classifier_kernel(const float4* __restrict__ h4,
                                                         const float* __restrict__ Wc,
                                                         const float* __restrict__ bc,
                                                         float* __restrict__ logits,
                                                         int n) {
  __shared__ float sW[2048];
  __shared__ float sb[16];
  int t = threadIdx.x;
#pragma unroll
  for (int i = 0; i < 8; ++i) sW[t + i * 256] = Wc[t + i * 256];
  if (t < 16) sb[t] = bc[t];
  __syncthreads();
  int node = blockIdx.x * 256 + t;
  if (node >= n) return;
  float acc[16];
#pragma unroll
  for (int o = 0; o < 16; ++o) acc[o] = sb[o];
  for (int c4 = 0; c4 < 32; ++c4) {
    float4 hv = h4[(unsigned)node * 32 + c4];
    const float* w = &sW[c4 * 64];
#pragma unroll
    for (int o = 0; o < 16; ++o) {
      acc[o] = fmaf(hv.x, w[o], acc[o]);
      acc[o] = fmaf(hv.y, w[16 + o], acc[o]);
      acc[o] = fmaf(hv.z, w[32 + o], acc[o]);
      acc[o] = fmaf(hv.w, w[48 + o], acc[o]);
    }
  }
#pragma unroll
  for (int q = 0; q < 4; ++q)
    *(float4*)&logits[(size_t)node * 16 + q * 4] =
        make_float4(acc[q * 4], acc[q * 4 + 1], acc[q * 4 + 2], acc[q * 4 + 3]);
}

// ---------------------------------------------------------------------------

extern "C" void kernel_launch(void* const* d_in, const int* in_sizes, int n_in,
                              void* d_out, int out_size, void* d_ws, size_t ws_size,
                              hipStream_t stream) {
  const float* x    = (const float*)d_in[0];
  const int*   ei   = (const int*)d_in[1];
  const float* Wl1  = (const float*)d_in[3];
  const float* Wr1  = (const float*)d_in[4];
  const float* att1 = (const float*)d_in[5];
  const float* b1   = (const float*)d_in[6];
  const float* Wl2  = (const float*)d_in[7];
  const float* Wr2  = (const float*)d_in[8];
  const float* att2 = (const float*)d_in[9];
  const float* b2   = (const float*)d_in[10];
  const float* Wc   = (const float*)d_in[11];
  const float* bc   = (const float*)d_in[12];

  const int N = in_sizes[0] / 128;
  const int E = in_sizes[1] / 2;

  float* outp   = (float*)d_out;
  float* logits = outp;                   // N*16 fp32
  float* hout   = outp + (size_t)N * 16;  // N*128 fp32 region
  // h1 bf16 hi/lo staged in the hout region (overwritten by fp32 h2 later)
  unsigned short* regionA = (unsigned short*)hout;
  unsigned short* regionB = regionA + (size_t)N * 128;

  char* ws = (char*)d_ws;
  __half* xlbuf = (__half*)ws;                ws += (size_t)N * 128 * 2;
  __half* xrbuf = (__half*)ws;                ws += (size_t)N * 128 * 2;
  unsigned short* WT1h = (unsigned short*)ws; ws += 256 * 128 * 2;
  unsigned short* WT1l = (unsigned short*)ws; ws += 256 * 128 * 2;
  unsigned short* WT2h = (unsigned short*)ws; ws += 256 * 128 * 2;
  unsigned short* WT2l = (unsigned short*)ws; ws += 256 * 128 * 2;
  int* cnt       = (int*)ws;                  ws += (size_t)N * 4;
  int* row_start = (int*)ws;                  ws += (size_t)(N + 1) * 4;
  int* wpos      = (int*)ws;                  ws += (size_t)N * 4;
  int* bsum      = (int*)ws;                  ws += 256 * 4;
  int* csr       = (int*)ws;                  ws += (size_t)(E + N + 16) * 4;

  const int* esrc = ei;
  const int* edst = ei + E;

  int gN = (N + 255) / 256, gE = (E + 255) / 256;
  dim3 gGemm((N + 127) / 128, 4);
  int gAttn = (N + 3) / 4;

  // CSR build (self loops embedded: counts+1, csr[beg]=node)
  zero_i32<<<gN, 256, 0, stream>>>(cnt, N);
  count_kernel<<<gE, 256, 0, stream>>>(edst, cnt, E);
  scan_blk<<<gN, 256, 0, stream>>>(cnt, row_start, bsum, N);
  scan_bsum<<<1, 256, 0, stream>>>(bsum, gN, row_start, N);
  scan_add<<<gN, 256, 0, stream>>>(row_start, bsum, wpos, csr, N);
  scatter_kernel<<<gE, 256, 0, stream>>>(esrc, edst, wpos, csr, E);
  zero_i32<<<1, 256, 0, stream>>>(csr + E + N, 16);  // pad for masked tail

  // weight conversions (both layers, one dispatch)
  convert_W<<<256, 256, 0, stream>>>(Wl1, Wr1, Wl2, Wr2, WT1h, WT1l, WT2h, WT2l);

  // layer 1 (GEMM reads fp32 x, splits inline; writes fp16 xl/xr)
  gemm_mfma<true><<<gGemm, 256, 0, stream>>>(x, nullptr, nullptr, WT1h, WT1l,
                                             xlbuf, xrbuf, N);
  gat_attn<<<gAttn, 256, 0, stream>>>(xlbuf, xrbuf, row_start, csr, att1, b1,
                                      nullptr, regionA, regionB, N);

  // layer 2 (reads h1 bf16 hi/lo; writes fp16 xl/xr)
  gemm_mfma<false><<<gGemm, 256, 0, stream>>>(nullptr, regionA, regionB, WT2h, WT2l,
                                              xlbuf, xrbuf, N);
  gat_attn<<<gAttn, 256, 0, stream>>>(xlbuf, xrbuf, row_start, csr, att2, b2,
                                      hout, nullptr, nullptr, N);

  // classifier
  classifier_kernel<<<(N + 255) / 256, 256, 0, stream>>>((const float4*)hout, Wc, bc,
                                                         logits, N);
}

// Round 8
// 335.739 us; speedup vs baseline: 1.9963x; 1.0332x over previous
//
#include <hip/hip_runtime.h>
#include <hip/hip_fp16.h>

// ---------------------------------------------------------------------------
// GATv2 x2 + classifier. N=50000, E=800000, IN=128, HEADS=4, HID=32, OUT=16.
// R8: scatter_kernel v2 -- node-sliced (8 slices matching XCD count via
//     blockIdx&7) so each csr slice (~400KB) stays in one XCD's L2 and the
//     random 4B writes combine (WRITE_SIZE 52.8MB -> ~5MB predicted; was
//     64B writeback per edge). dst[] read 8x sequentially (cheap).
// ---------------------------------------------------------------------------

#define LOG2E 1.4426950408889634f

typedef short bf16x8 __attribute__((ext_vector_type(8)));
typedef float f32x4 __attribute__((ext_vector_type(4)));

__device__ __forceinline__ unsigned short f2bf(float f) {
  union { float f; unsigned u; } x; x.f = f;
  unsigned r = x.u + 0x7fffu + ((x.u >> 16) & 1u);
  return (unsigned short)(r >> 16);
}
__device__ __forceinline__ float bf2f(unsigned short h) {
  union { unsigned u; float f; } x; x.u = ((unsigned)h) << 16;
  return x.f;
}
__device__ __forceinline__ void split4(float4 v, ushort4& h, ushort4& l) {
  h.x = f2bf(v.x); l.x = f2bf(v.x - bf2f(h.x));
  h.y = f2bf(v.y); l.y = f2bf(v.y - bf2f(h.y));
  h.z = f2bf(v.z); l.z = f2bf(v.z - bf2f(h.z));
  h.w = f2bf(v.w); l.w = f2bf(v.w - bf2f(h.w));
}

// ------------------------------ CSR build ----------------------------------

__global__ __launch_bounds__(256) void zero_i32(int* __restrict__ p, int n) {
  int i = blockIdx.x * 256 + threadIdx.x;
  if (i < n) p[i] = 0;
}

__global__ __launch_bounds__(256) void count_kernel(const int* __restrict__ dst,
                                                    int* __restrict__ cnt, int E) {
  int i = blockIdx.x * 256 + threadIdx.x;
  if (i < E) atomicAdd(&cnt[dst[i]], 1);
}

// per-block scan of (cnt[i]+1)  (+1 = self loop slot)
__global__ __launch_bounds__(256) void scan_blk(const int* __restrict__ cnt,
                                                int* __restrict__ excl,
                                                int* __restrict__ bsum, int n) {
  __shared__ int s[256];
  int t = threadIdx.x, i = blockIdx.x * 256 + t;
  int v = (i < n) ? (cnt[i] + 1) : 0;
  s[t] = v;
  __syncthreads();
#pragma unroll
  for (int off = 1; off < 256; off <<= 1) {
    int u = (t >= off) ? s[t - off] : 0;
    __syncthreads();
    s[t] += u;
    __syncthreads();
  }
  if (i < n) excl[i] = s[t] - v;
  if (t == 255) bsum[blockIdx.x] = s[255];
}

__global__ __launch_bounds__(256) void scan_bsum(int* __restrict__ bsum, int nb,
                                                 int* __restrict__ row_start, int n) {
  __shared__ int s[256];
  int t = threadIdx.x;
  int v = (t < nb) ? bsum[t] : 0;
  s[t] = v;
  __syncthreads();
#pragma unroll
  for (int off = 1; off < 256; off <<= 1) {
    int u = (t >= off) ? s[t - off] : 0;
    __syncthreads();
    s[t] += u;
    __syncthreads();
  }
  if (t < nb) bsum[t] = s[t] - v;
  if (t == 255) row_start[n] = s[255];
}

// add block offsets; write self-loop entry; wpos starts past it
__global__ __launch_bounds__(256) void scan_add(int* __restrict__ row_start,
                                                const int* __restrict__ bsum,
                                                int* __restrict__ wpos,
                                                int* __restrict__ csr, int n) {
  int i = blockIdx.x * 256 + threadIdx.x;
  if (i < n) {
    int r = row_start[i] + bsum[blockIdx.x];
    row_start[i] = r;
    wpos[i] = r + 1;
    csr[r] = i;  // self loop first in each row
  }
}

// node-sliced scatter: slice = blockIdx&7 (XCD round-robin heuristic),
// chunk = blockIdx>>3. Each csr slice stays in one XCD's L2 -> writes combine.
__global__ __launch_bounds__(256) void scatter_kernel(const int* __restrict__ src,
                                                      const int* __restrict__ dst,
                                                      int* __restrict__ wpos,
                                                      int* __restrict__ csr,
                                                      int E, int sliceSize) {
  int slice = blockIdx.x & 7;
  int chunk = blockIdx.x >> 3;
  int nchunk = gridDim.x >> 3;
  int lo = slice * sliceSize, hi = lo + sliceSize;
  int per = (E + nchunk - 1) / nchunk;
  int b = chunk * per;
  int e = min(b + per, E);
  for (int i = b + threadIdx.x; i < e; i += 256) {
    int d = dst[i];
    if (d >= lo && d < hi) {
      int p = atomicAdd(&wpos[d], 1);
      csr[p] = src[i];
    }
  }
}

// --------------------------- weight converts -------------------------------
// both layers in one dispatch: 256 blocks, blocks 0-127 layer1, 128-255 layer2
__global__ __launch_bounds__(256) void convert_W(const float* __restrict__ Wl1,
                                                 const float* __restrict__ Wr1,
                                                 const float* __restrict__ Wl2,
                                                 const float* __restrict__ Wr2,
                                                 unsigned short* __restrict__ BT1h,
                                                 unsigned short* __restrict__ BT1l,
                                                 unsigned short* __restrict__ BT2h,
                                                 unsigned short* __restrict__ BT2l) {
  int b = blockIdx.x;
  const float* Wl = (b < 128) ? Wl1 : Wl2;
  const float* Wr = (b < 128) ? Wr1 : Wr2;
  unsigned short* BTh = (b < 128) ? BT1h : BT2h;
  unsigned short* BTl = (b < 128) ? BT1l : BT2l;
  int idx = (b & 127) * 256 + threadIdx.x;  // 0..32767
  int col = idx >> 7, k = idx & 127;
  float v = (col < 128) ? Wl[k * 128 + col] : Wr[k * 128 + (col - 128)];
  unsigned short h = f2bf(v);
  BTh[idx] = h;
  BTl[idx] = f2bf(v - bf2f(h));
}

// ------------------------------ MFMA GEMM ----------------------------------
// C[N x 256] = A[N x 128] @ W[128 x 256], split-bf16 3-term; C stored fp16.
template <bool FP32IN>
__global__ __launch_bounds__(256) void gemm_mfma(
    const float* __restrict__ Af,
    const unsigned short* __restrict__ Ah, const unsigned short* __restrict__ Al,
    const unsigned short* __restrict__ BTh, const unsigned short* __restrict__ BTl,
    __half* __restrict__ Cl, __half* __restrict__ Cr, int nrows) {
  __shared__ unsigned short sAh[128 * 32], sAl[128 * 32];
  __shared__ unsigned short sBh[64 * 32], sBl[64 * 32];
  int tid = threadIdx.x;
  int wave = tid >> 6, lane = tid & 63;
  int rowBase = blockIdx.x * 128;
  int colBase = blockIdx.y * 64;
  int rowHalf = (wave >> 1) * 64;
  int colHalf = (wave & 1) * 32;
  int l15 = lane & 15, quad = lane >> 4;

  f32x4 acc[4][2];
#pragma unroll
  for (int m = 0; m < 4; ++m)
#pragma unroll
    for (int n = 0; n < 2; ++n) acc[m][n] = (f32x4){0.f, 0.f, 0.f, 0.f};

  for (int kc = 0; kc < 4; ++kc) {
#pragma unroll
    for (int i = 0; i < 2; ++i) {
      int idx = tid + i * 256;  // 0..511
      int row = idx >> 2, seg = idx & 3;
      int gr = rowBase + row;
      if (FP32IN) {
        float4 v0 = make_float4(0.f, 0.f, 0.f, 0.f), v1 = v0;
        if (gr < nrows) {
          v0 = *(const float4*)&Af[(size_t)gr * 128 + kc * 32 + seg * 8];
          v1 = *(const float4*)&Af[(size_t)gr * 128 + kc * 32 + seg * 8 + 4];
        }
        ushort4 h0, l0, h1, l1;
        split4(v0, h0, l0);
        split4(v1, h1, l1);
        *(ushort4*)&sAh[row * 32 + seg * 8] = h0;
        *(ushort4*)&sAh[row * 32 + seg * 8 + 4] = h1;
        *(ushort4*)&sAl[row * 32 + seg * 8] = l0;
        *(ushort4*)&sAl[row * 32 + seg * 8 + 4] = l1;
      } else {
        uint4 vh = make_uint4(0, 0, 0, 0), vl = make_uint4(0, 0, 0, 0);
        if (gr < nrows) {
          vh = *(const uint4*)&Ah[(size_t)gr * 128 + kc * 32 + seg * 8];
          vl = *(const uint4*)&Al[(size_t)gr * 128 + kc * 32 + seg * 8];
        }
        *(uint4*)&sAh[row * 32 + seg * 8] = vh;
        *(uint4*)&sAl[row * 32 + seg * 8] = vl;
      }
    }
    {
      int col = tid >> 2, seg = tid & 3;
      *(uint4*)&sBh[col * 32 + seg * 8] =
          *(const uint4*)&BTh[(size_t)(colBase + col) * 128 + kc * 32 + seg * 8];
      *(uint4*)&sBl[col * 32 + seg * 8] =
          *(const uint4*)&BTl[(size_t)(colBase + col) * 128 + kc * 32 + seg * 8];
    }
    __syncthreads();

    bf16x8 afh[4], afl[4], bfh[2], bfl[2];
#pragma unroll
    for (int m = 0; m < 4; ++m) {
      int r = rowHalf + m * 16 + l15;
      afh[m] = *(const bf16x8*)&sAh[r * 32 + quad * 8];
      afl[m] = *(const bf16x8*)&sAl[r * 32 + quad * 8];
    }
#pragma unroll
    for (int n = 0; n < 2; ++n) {
      int cc = colHalf + n * 16 + l15;
      bfh[n] = *(const bf16x8*)&sBh[cc * 32 + quad * 8];
      bfl[n] = *(const bf16x8*)&sBl[cc * 32 + quad * 8];
    }
#pragma unroll
    for (int m = 0; m < 4; ++m)
#pragma unroll
      for (int n = 0; n < 2; ++n) {
        acc[m][n] = __builtin_amdgcn_mfma_f32_16x16x32_bf16(afh[m], bfh[n], acc[m][n], 0, 0, 0);
        acc[m][n] = __builtin_amdgcn_mfma_f32_16x16x32_bf16(afh[m], bfl[n], acc[m][n], 0, 0, 0);
        acc[m][n] = __builtin_amdgcn_mfma_f32_16x16x32_bf16(afl[m], bfh[n], acc[m][n], 0, 0, 0);
      }
    __syncthreads();
  }

  bool isL = (colBase < 128);
  __half* __restrict__ C = isL ? Cl : Cr;
  int cb = (isL ? colBase : colBase - 128) + colHalf;
#pragma unroll
  for (int m = 0; m < 4; ++m)
#pragma unroll
    for (int r = 0; r < 4; ++r) {
      int grow = rowBase + rowHalf + m * 16 + quad * 4 + r;
      if (grow < nrows) {
#pragma unroll
        for (int n = 0; n < 2; ++n)
          C[(size_t)grow * 128 + cb + n * 16 + l15] = __float2half(acc[m][n][r]);
      }
    }
}

// ------------------------------ attention ----------------------------------
// One wave per node; 16 lanes/edge (8 ch/lane, one b128 fp16 load);
// 4 edge-slots/wave. Main loop 16 edges/iter, tail 4 edges/iter.
// Self loop lives in csr (csr[beg] = node).
__global__ __launch_bounds__(256) void gat_attn(const __half* __restrict__ xl,
                                                const __half* __restrict__ xr,
                                                const int* __restrict__ row_start,
                                                const int* __restrict__ csr,
                                                const float* __restrict__ att,
                                                const float* __restrict__ bias,
                                                float* __restrict__ ofp,
                                                unsigned short* __restrict__ oh_hi,
                                                unsigned short* __restrict__ oh_lo,
                                                int n_nodes) {
  int node = blockIdx.x * 4 + (threadIdx.x >> 6);
  if (node >= n_nodes) return;
  int lane = threadIdx.x & 63;
  int slot = lane >> 4;
  int l15 = lane & 15;
  int c0 = l15 * 8;

  // xr row (fp16 -> fp32)
  float fxr[8];
  {
    uint4 raw = *(const uint4*)&xr[(size_t)node * 128 + c0];
    const __half* hp = (const __half*)&raw;
#pragma unroll
    for (int k = 0; k < 8; ++k) fxr[k] = __half2float(hp[k]);
  }
  // att row, pre-scaled: a06 = 0.6*log2e*a, a04 = 0.4*log2e*a
  float a06[8], a04[8];
  {
    float4 a0 = *(const float4*)&att[c0];
    float4 a1 = *(const float4*)&att[c0 + 4];
    float av[8] = {a0.x, a0.y, a0.z, a0.w, a1.x, a1.y, a1.z, a1.w};
    const float C06 = 0.6f * LOG2E, C04 = 0.4f * LOG2E;
#pragma unroll
    for (int k = 0; k < 8; ++k) { a06[k] = av[k] * C06; a04[k] = av[k] * C04; }
  }

  float acc[8];
#pragma unroll
  for (int k = 0; k < 8; ++k) acc[k] = 0.f;
  float lsum = 0.f;

#define EDGE_BODY(SRC, PVALID)                                                 \
  {                                                                            \
    uint4 raw = *(const uint4*)&xl[(size_t)(unsigned)(SRC)*128 + c0];          \
    const __half* hp = (const __half*)&raw;                                    \
    float e = 0.f;                                                             \
    _Pragma("unroll") for (int k = 0; k < 8; ++k) {                            \
      float t = __half2float(hp[k]) + fxr[k];                                  \
      e = fmaf(a06[k], t, e);                                                  \
      e = fmaf(a04[k], fabsf(t), e);                                           \
    }                                                                          \
    e += __shfl_xor(e, 1);                                                     \
    e += __shfl_xor(e, 2);                                                     \
    float p = (PVALID) ? __builtin_amdgcn_exp2f(e) : 0.f;                      \
    lsum += p;                                                                 \
    _Pragma("unroll") for (int k = 0; k < 8; ++k)                              \
        acc[k] = fmaf(p, __half2float(hp[k]), acc[k]);                         \
  }

  int beg = row_start[node], end = row_start[node + 1];
  int deg = end - beg;  // includes self
  int fullEnd = beg + (deg & ~15);

  for (int base = beg; base < fullEnd; base += 16) {
    int b0 = base + 4 * slot;
    int s0 = csr[b0], s1 = csr[b0 + 1], s2 = csr[b0 + 2], s3 = csr[b0 + 3];
    EDGE_BODY(s0, true);
    EDGE_BODY(s1, true);
    EDGE_BODY(s2, true);
    EDGE_BODY(s3, true);
  }
  for (int base = fullEnd; base < end; base += 4) {  // csr padded by 16
    int idx = base + slot;
    int src = csr[idx];
    EDGE_BODY(src, idx < end);
  }
#undef EDGE_BODY

  // merge the 4 slots (same channels live in lanes with equal l15)
  lsum += __shfl_xor(lsum, 16);
  lsum += __shfl_xor(lsum, 32);
#pragma unroll
  for (int k = 0; k < 8; ++k) {
    acc[k] += __shfl_xor(acc[k], 16);
    acc[k] += __shfl_xor(acc[k], 32);
  }

  if (slot == 0) {
    float4 b0v = *(const float4*)&bias[c0];
    float4 b1v = *(const float4*)&bias[c0 + 4];
    float bv[8] = {b0v.x, b0v.y, b0v.z, b0v.w, b1v.x, b1v.y, b1v.z, b1v.w};
    float inv = 1.f / (lsum + 1e-16f);
    float o[8];
#pragma unroll
    for (int k = 0; k < 8; ++k) {
      float v = fmaf(acc[k], inv, bv[k]);
      o[k] = fmaf(0.495f, fabsf(v), 0.505f * v);  // leaky 0.01
    }
    if (ofp) {
      *(float4*)&ofp[(size_t)node * 128 + c0] = make_float4(o[0], o[1], o[2], o[3]);
      *(float4*)&ofp[(size_t)node * 128 + c0 + 4] = make_float4(o[4], o[5], o[6], o[7]);
    }
    if (oh_hi) {
      ushort4 h0, l0, h1, l1;
      split4(make_float4(o[0], o[1], o[2], o[3]), h0, l0);
      split4(make_float4(o[4], o[5], o[6], o[7]), h1, l1);
      *(ushort4*)&oh_hi[(size_t)node * 128 + c0] = h0;
      *(ushort4*)&oh_hi[(size_t)node * 128 + c0 + 4] = h1;
      *(ushort4*)&oh_lo[(size_t)node * 128 + c0] = l0;
      *(ushort4*)&oh_lo[(size_t)node * 128 + c0 + 4] = l1;
    }
  }
}

// ------------------------------ classifier ---------------------------------
__global__ __launch_bounds__(256) void classifier_kernel(const float4* __restrict__ h4,
                                                         const float* __restrict__ Wc,
                                                         const float* __restrict__ bc,
                                                         float* __restrict__ logits,
                                                         int n) {
  __shared__ float sW[2048];
  __shared__ float sb[16];
  int t = threadIdx.x;
#pragma unroll
  for (int i = 0; i < 8; ++i) sW[t + i * 256] = Wc[t + i * 256];
  if (t < 16) sb[t] = bc[t];
  __syncthreads();
  int node = blockIdx.x * 256 + t;
  if (node >= n) return;
  float acc[16];
#pragma unroll
  for (int o = 0; o < 16; ++o) acc[o] = sb[o];
  for (int c4 = 0; c4 < 32; ++c4) {
    float4 hv = h4[(unsigned)node * 32 + c4];
    const float* w = &sW[c4 * 64];
#pragma unroll
    for (int o = 0; o < 16; ++o) {
      acc[o] = fmaf(hv.x, w[o], acc[o]);
      acc[o] = fmaf(hv.y, w[16 + o], acc[o]);
      acc[o] = fmaf(hv.z, w[32 + o], acc[o]);
      acc[o] = fmaf(hv.w, w[48 + o], acc[o]);
    }
  }
#pragma unroll
  for (int q = 0; q < 4; ++q)
    *(float4*)&logits[(size_t)node * 16 + q * 4] =
        make_float4(acc[q * 4], acc[q * 4 + 1], acc[q * 4 + 2], acc[q * 4 + 3]);
}

// ---------------------------------------------------------------------------

extern "C" void kernel_launch(void* const* d_in, const int* in_sizes, int n_in,
                              void* d_out, int out_size, void* d_ws, size_t ws_size,
                              hipStream_t stream) {
  const float* x    = (const float*)d_in[0];
  const int*   ei   = (const int*)d_in[1];
  const float* Wl1  = (const float*)d_in[3];
  const float* Wr1  = (const float*)d_in[4];
  const float* att1 = (const float*)d_in[5];
  const float* b1   = (const float*)d_in[6];
  const float* Wl2  = (const float*)d_in[7];
  const float* Wr2  = (const float*)d_in[8];
  const float* att2 = (const float*)d_in[9];
  const float* b2   = (const float*)d_in[10];
  const float* Wc   = (const float*)d_in[11];
  const float* bc   = (const float*)d_in[12];

  const int N = in_sizes[0] / 128;
  const int E = in_sizes[1] / 2;

  float* outp   = (float*)d_out;
  float* logits = outp;                   // N*16 fp32
  float* hout   = outp + (size_t)N * 16;  // N*128 fp32 region
  // h1 bf16 hi/lo staged in the hout region (overwritten by fp32 h2 later)
  unsigned short* regionA = (unsigned short*)hout;
  unsigned short* regionB = regionA + (size_t)N * 128;

  char* ws = (char*)d_ws;
  __half* xlbuf = (__half*)ws;                ws += (size_t)N * 128 * 2;
  __half* xrbuf = (__half*)ws;                ws += (size_t)N * 128 * 2;
  unsigned short* WT1h = (unsigned short*)ws; ws += 256 * 128 * 2;
  unsigned short* WT1l = (unsigned short*)ws; ws += 256 * 128 * 2;
  unsigned short* WT2h = (unsigned short*)ws; ws += 256 * 128 * 2;
  unsigned short* WT2l = (unsigned short*)ws; ws += 256 * 128 * 2;
  int* cnt       = (int*)ws;                  ws += (size_t)N * 4;
  int* row_start = (int*)ws;                  ws += (size_t)(N + 1) * 4;
  int* wpos      = (int*)ws;                  ws += (size_t)N * 4;
  int* bsum      = (int*)ws;                  ws += 256 * 4;
  int* csr       = (int*)ws;                  ws += (size_t)(E + N + 16) * 4;

  const int* esrc = ei;
  const int* edst = ei + E;

  int gN = (N + 255) / 256, gE = (E + 255) / 256;
  dim3 gGemm((N + 127) / 128, 4);
  int gAttn = (N + 3) / 4;
  int sliceSize = (N + 7) / 8;

  // CSR build (self loops embedded: counts+1, csr[beg]=node)
  zero_i32<<<gN, 256, 0, stream>>>(cnt, N);
  count_kernel<<<gE, 256, 0, stream>>>(edst, cnt, E);
  scan_blk<<<gN, 256, 0, stream>>>(cnt, row_start, bsum, N);
  scan_bsum<<<1, 256, 0, stream>>>(bsum, gN, row_start, N);
  scan_add<<<gN, 256, 0, stream>>>(row_start, bsum, wpos, csr, N);
  scatter_kernel<<<1024, 256, 0, stream>>>(esrc, edst, wpos, csr, E, sliceSize);
  zero_i32<<<1, 256, 0, stream>>>(csr + E + N, 16);  // pad for masked tail

  // weight conversions (both layers, one dispatch)
  convert_W<<<256, 256, 0, stream>>>(Wl1, Wr1, Wl2, Wr2, WT1h, WT1l, WT2h, WT2l);

  // layer 1 (GEMM reads fp32 x, splits inline; writes fp16 xl/xr)
  gemm_mfma<true><<<gGemm, 256, 0, stream>>>(x, nullptr, nullptr, WT1h, WT1l,
                                             xlbuf, xrbuf, N);
  gat_attn<<<gAttn, 256, 0, stream>>>(xlbuf, xrbuf, row_start, csr, att1, b1,
                                      nullptr, regionA, regionB, N);

  // layer 2 (reads h1 bf16 hi/lo; writes fp16 xl/xr)
  gemm_mfma<false><<<gGemm, 256, 0, stream>>>(nullptr, regionA, regionB, WT2h, WT2l,
                                              xlbuf, xrbuf, N);
  gat_attn<<<gAttn, 256, 0, stream>>>(xlbuf, xrbuf, row_start, csr, att2, b2,
                                      hout, nullptr, nullptr, N);

  // classifier
  classifier_kernel<<<(N + 255) / 256, 256, 0, stream>>>((const float4*)hout, Wc, bc,
                                                         logits, N);
}